// Round 4
// baseline (341.433 us; speedup 1.0000x reference)
//
#include <hip/hip_runtime.h>
#include <hip/hip_bf16.h>
#include <stdint.h>

typedef unsigned short u16;
typedef unsigned int u32;
typedef __attribute__((ext_vector_type(8))) short short8;   // 8 bf16 (4 VGPRs) MFMA operand
typedef __attribute__((ext_vector_type(4))) float f32x4;    // MFMA accumulator
typedef __attribute__((ext_vector_type(2))) float f32x2;    // packed-fp32 (v_pk_*) carrier
typedef __attribute__((ext_vector_type(4))) unsigned short u16x4;
typedef __attribute__((ext_vector_type(2))) unsigned int u32x2;

#define DEVFN static __device__ __forceinline__

// ---------- helpers ----------

DEVFN u16 f2bf(float f) {  // RNE float->bf16 (finite inputs)
  u32 u = __float_as_uint(f);
  u = (u + 0x7FFFu + ((u >> 16) & 1u)) >> 16;
  return (u16)u;
}

DEVFN float bf2f(u16 v) { return __uint_as_float((u32)v << 16); }

DEVFN u32 cvtpk_bf16(float lo, float hi) {  // T12: packed f32x2 -> 2xbf16 in one u32
  u32 r;
  asm("v_cvt_pk_bf16_f32 %0, %1, %2" : "=v"(r) : "v"(lo), "v"(hi));
  return r;
}

DEVFN void gll16(const void* g, void* l) {  // async global->LDS, 16B/lane
  __builtin_amdgcn_global_load_lds((const __attribute__((address_space(1))) u32*)g,
                                   (__attribute__((address_space(3))) u32*)l, 16, 0, 0);
}

// ---------- fused context-sum + bf16 convert (single pass over x) ----------
// grid 256 = [b 2][128 chunks of 16 rows]; 256 threads; thread owns 4 consecutive cols.
__global__ void ctx_cvt_kernel(const float* __restrict__ x, float* __restrict__ ctx,
                               u16* __restrict__ xbf) {
  int blk = blockIdx.x;
  int b = blk >> 7;
  int s0 = (blk & 127) * 16;
  int t = threadIdx.x;
  const float* xb = x + ((size_t)b * 2048 + s0) * 1024 + t * 4;
  u16* ob = xbf + ((size_t)b * 2048 + s0) * 1024 + t * 4;
  float4 sum = {0.f, 0.f, 0.f, 0.f};
#pragma unroll
  for (int s = 0; s < 16; ++s) {
    float4 v = *(const float4*)(xb + (size_t)s * 1024);
    sum.x += v.x;
    sum.y += v.y;
    sum.z += v.z;
    sum.w += v.w;
    u16x4 o = {f2bf(v.x), f2bf(v.y), f2bf(v.z), f2bf(v.w)};
    *(u16x4*)(ob + (size_t)s * 1024) = o;
  }
  float* c = ctx + b * 1024 + t * 4;
  atomicAdd(c + 0, sum.x);
  atomicAdd(c + 1, sum.y);
  atomicAdd(c + 2, sum.z);
  atomicAdd(c + 3, sum.w);
}

// stage 1: h = gelu(ctx/2048 @ W1 + b1). grid 16 = 2b x 8 j-chunks of 64.
__global__ void adaptive1_kernel(const float* __restrict__ ctx, const float* __restrict__ W1,
                                 const float* __restrict__ b1, float* __restrict__ hbuf) {
  int b = blockIdx.x >> 3, jb = blockIdx.x & 7;
  int t = threadIdx.x;
  int j = jb * 64 + (t & 63);
  int part = t >> 6;  // 0..3, each covers 256 d's
  __shared__ float ctxs[1024];
  __shared__ float partial[4][64];
  for (int i = t; i < 1024; i += 256) ctxs[i] = ctx[b * 1024 + i] * (1.0f / 2048.0f);
  __syncthreads();
  float a0 = 0.f, a1 = 0.f;
  int d0 = part * 256;
  for (int d = d0; d < d0 + 256; d += 2) {
    a0 += ctxs[d] * W1[(size_t)d * 512 + j];
    a1 += ctxs[d + 1] * W1[(size_t)(d + 1) * 512 + j];
  }
  partial[part][t & 63] = a0 + a1;
  __syncthreads();
  if (t < 64) {
    float acc = b1[j] + ((partial[0][t] + partial[1][t]) + (partial[2][t] + partial[3][t]));
    hbuf[b * 512 + j] = 0.5f * acc * (1.0f + erff(acc * 0.70710678118654752f));  // exact gelu
  }
}

// stage 2: af = sigmoid(h @ W2 + b2); scale[b] = 1 + aw*mean(af). grid 2.
__global__ void adaptive2_kernel(const float* __restrict__ hbuf, const float* __restrict__ W2,
                                 const float* __restrict__ b2, const float* __restrict__ aw,
                                 float* __restrict__ scale) {
  int b = blockIdx.x;
  int t = threadIdx.x;
  __shared__ float part[256];
  int o = t & 15, seg = t >> 4;  // 16 segs x 32 j's
  float a = 0.f;
  for (int j = seg * 32; j < seg * 32 + 32; ++j) a += hbuf[b * 512 + j] * W2[(size_t)j * 16 + o];
  part[t] = a;
  __syncthreads();
  if (t < 16) {
    float acc = b2[t];
    for (int s2 = 0; s2 < 16; ++s2) acc += part[s2 * 16 + t];
    part[t] = 1.0f / (1.0f + __expf(-acc));
  }
  __syncthreads();
  if (t == 0) {
    float s = 0.f;
    for (int i = 0; i < 16; ++i) s += part[i];
    scale[b] = 1.0f + aw[0] * (s * (1.0f / 16.0f));
  }
}

// in: fp32 [K][N] row-major -> out: bf16 [N][K] row-major. grid (N/32, K/32), 256 thr.
__global__ void transpose_bf16_kernel(const float* __restrict__ in, u16* __restrict__ out,
                                      int K, int N) {
  __shared__ u16 tile[32][33];
  int n0 = blockIdx.x * 32, k0 = blockIdx.y * 32;
  int tc = threadIdx.x & 31, tr = threadIdx.x >> 5;  // tr in 0..7
  for (int i = tr; i < 32; i += 8)
    tile[i][tc] = f2bf(in[(size_t)(k0 + i) * N + n0 + tc]);
  __syncthreads();
  for (int i = tr; i < 32; i += 8)
    out[(size_t)(n0 + i) * K + k0 + tc] = tile[tc][i];
}

// ---------- GEMM mainloops: swizzled LDS + 2-phase double-buffer ----------
// C = A(MxK bf16 rowmajor) @ Bt(NxK bf16 rowmajor)^T, fp32 acc. K multiple of 32.
// acc[i][j] = mfma(bf[j], af[i]) -> lane&15 = m-row (i*16+lr), lg*4+r = n-col (j*16+lg*4+r):
// each lane owns 4 CONSECUTIVE output columns -> packed epilogue stores.

// 128x128 tile, 4 waves. As/Bs are [2][128*32] u16.
DEVFN void gemm_tile_mainloop(const u16* __restrict__ A, const u16* __restrict__ Bt,
                              int m0, int n0, int K, u16* As, u16* Bs, f32x4 acc[4][4]) {
  const int tid = threadIdx.x;
  const int lane = tid & 63, wid = tid >> 6;
  const int wr = wid >> 1, wc = wid & 1;
  const int lr = lane & 15, lg = lane >> 4;
  const int srow = tid >> 2;
  const int scol = ((tid & 3) ^ ((tid >> 3) & 3)) * 8;  // pre-swizzled source col (u16)
  const int axor = ((lr >> 1) & 3) << 4;                // read-side swizzle (bytes)

  const u16* ag0 = A + (size_t)(m0 + srow) * K + scol;
  const u16* ag1 = ag0 + (size_t)64 * K;
  const u16* bg0 = Bt + (size_t)(n0 + srow) * K + scol;
  const u16* bg1 = bg0 + (size_t)64 * K;

  // prologue: stage K-step 0 into buffer 0
  gll16(ag0, As + tid * 8);
  gll16(ag1, As + (tid + 256) * 8);
  gll16(bg0, Bs + tid * 8);
  gll16(bg1, Bs + (tid + 256) * 8);

  int cur = 0;
  for (int k0 = 0; k0 < K; k0 += 32) {
    __syncthreads();    // drains vmcnt: buffer `cur` staged & prev compute on cur^1 done
    if (k0 + 32 < K) {  // issue next-step stage; overlaps with compute below
      int nb = (cur ^ 1) * 4096;
      gll16(ag0 + k0 + 32, As + nb + tid * 8);
      gll16(ag1 + k0 + 32, As + nb + (tid + 256) * 8);
      gll16(bg0 + k0 + 32, Bs + nb + tid * 8);
      gll16(bg1 + k0 + 32, Bs + nb + (tid + 256) * 8);
    }
    const char* Ac = (const char*)(As + cur * 4096);
    const char* Bc = (const char*)(Bs + cur * 4096);
    short8 af[4], bf[4];
#pragma unroll
    for (int i = 0; i < 4; ++i)
      af[i] = *(const short8*)(Ac + (wr * 64 + i * 16 + lr) * 64 + ((lg * 16) ^ axor));
#pragma unroll
    for (int j = 0; j < 4; ++j)
      bf[j] = *(const short8*)(Bc + (wc * 64 + j * 16 + lr) * 64 + ((lg * 16) ^ axor));
#pragma unroll
    for (int i = 0; i < 4; ++i)
#pragma unroll
      for (int j = 0; j < 4; ++j)
        acc[i][j] = __builtin_amdgcn_mfma_f32_16x16x32_bf16(bf[j], af[i], acc[i][j], 0, 0, 0);
    cur ^= 1;
  }
}

// 64x64 tile, 4 waves (for skinny GEMM2). As/Bs are [2][64*32] u16.
DEVFN void gemm64_mainloop(const u16* __restrict__ A, const u16* __restrict__ Bt,
                           int m0, int n0, int K, u16* As, u16* Bs, f32x4 acc[2][2]) {
  const int tid = threadIdx.x;
  const int lane = tid & 63, wid = tid >> 6;
  const int wr = wid >> 1, wc = wid & 1;
  const int lr = lane & 15, lg = lane >> 4;
  const int srow = tid >> 2;
  const int scol = ((tid & 3) ^ ((tid >> 3) & 3)) * 8;
  const int axor = ((lr >> 1) & 3) << 4;

  const u16* ag = A + (size_t)(m0 + srow) * K + scol;
  const u16* bg = Bt + (size_t)(n0 + srow) * K + scol;
  gll16(ag, As + tid * 8);
  gll16(bg, Bs + tid * 8);

  int cur = 0;
  for (int k0 = 0; k0 < K; k0 += 32) {
    __syncthreads();
    if (k0 + 32 < K) {
      int nb = (cur ^ 1) * 2048;
      gll16(ag + k0 + 32, As + nb + tid * 8);
      gll16(bg + k0 + 32, Bs + nb + tid * 8);
    }
    const char* Ac = (const char*)(As + cur * 2048);
    const char* Bc = (const char*)(Bs + cur * 2048);
    short8 af[2], bf[2];
#pragma unroll
    for (int i = 0; i < 2; ++i)
      af[i] = *(const short8*)(Ac + (wr * 32 + i * 16 + lr) * 64 + ((lg * 16) ^ axor));
#pragma unroll
    for (int j = 0; j < 2; ++j)
      bf[j] = *(const short8*)(Bc + (wc * 32 + j * 16 + lr) * 64 + ((lg * 16) ^ axor));
#pragma unroll
    for (int i = 0; i < 2; ++i)
#pragma unroll
      for (int j = 0; j < 2; ++j)
        acc[i][j] = __builtin_amdgcn_mfma_f32_16x16x32_bf16(bf[j], af[i], acc[i][j], 0, 0, 0);
    cur ^= 1;
  }
}

// GEMM1: qkv = x_bf16 @ WqkvT^T + bqkv -> Q[b,s,h,d] (pre-scaled 1/8), K[b,s,h,d],
// V^T[b,h,d,s]. grid 768 1-D with XCD swizzle.
__global__ __launch_bounds__(256) void gemm_qkv_kernel(
    const u16* __restrict__ A, const u16* __restrict__ Bt, const float* __restrict__ bias,
    u16* __restrict__ Qb, u16* __restrict__ Kb, u16* __restrict__ Vt) {
  __shared__ __align__(16) u16 As[2 * 128 * 32];
  __shared__ __align__(16) u16 Bs[2 * 128 * 32];
  f32x4 acc[4][4];
  const f32x4 z = {0.f, 0.f, 0.f, 0.f};
#pragma unroll
  for (int i = 0; i < 4; ++i)
#pragma unroll
    for (int j = 0; j < 4; ++j) acc[i][j] = z;
  int lin = blockIdx.x;
  int swz = (lin & 7) * 96 + (lin >> 3);  // 768 = 8*96, bijective
  int n0 = (swz % 24) * 128, m0 = (swz / 24) * 128;
  gemm_tile_mainloop(A, Bt, m0, n0, 1024, As, Bs, acc);

  const int lane = threadIdx.x & 63, wid = threadIdx.x >> 6;
  const int wr = wid >> 1, wc = wid & 1, lr = lane & 15, lg = lane >> 4;
#pragma unroll
  for (int i = 0; i < 4; ++i) {
    int m = m0 + wr * 64 + i * 16 + lr;  // token row
#pragma unroll
    for (int j = 0; j < 4; ++j) {
      int nb = n0 + wc * 64 + j * 16 + lg * 4;  // col base, +r consecutive
      float4 bv = *(const float4*)&bias[nb];
      int c3 = nb >> 10;
      if (c3 == 2) {  // V^T: 4 consecutive d at fixed s -> scalar stores
        int bb = m >> 11, ss = m & 2047;
        int hh = (nb >> 6) & 15, dd = nb & 63;
        size_t vb_ = (((size_t)bb * 16 + hh) * 64 + dd) * 2048 + ss;
        Vt[vb_] = f2bf(acc[i][j][0] + bv.x);
        Vt[vb_ + 2048] = f2bf(acc[i][j][1] + bv.y);
        Vt[vb_ + 4096] = f2bf(acc[i][j][2] + bv.z);
        Vt[vb_ + 6144] = f2bf(acc[i][j][3] + bv.w);
      } else {
        u16* dst = (c3 == 0) ? Qb : Kb;
        float qs = (c3 == 0) ? 0.125f : 1.0f;  // fold 1/sqrt(dh) into Q
        u16x4 o = {f2bf((acc[i][j][0] + bv.x) * qs), f2bf((acc[i][j][1] + bv.y) * qs),
                   f2bf((acc[i][j][2] + bv.z) * qs), f2bf((acc[i][j][3] + bv.w) * qs)};
        *(u16x4*)&dst[(size_t)m * 1024 + (nb & 1023)] = o;
      }
    }
  }
}

// GEMM2: out = (attn_bf16 @ WoT^T + bo) * scale[b], fp32 out. 64x64 tiles, grid 1024 1-D.
__global__ __launch_bounds__(256) void gemm_out_kernel(
    const u16* __restrict__ A, const u16* __restrict__ Bt, const float* __restrict__ bo,
    const float* __restrict__ scale, float* __restrict__ out) {
  __shared__ __align__(16) u16 As[2 * 64 * 32];
  __shared__ __align__(16) u16 Bs[2 * 64 * 32];
  f32x4 acc[2][2];
  const f32x4 z = {0.f, 0.f, 0.f, 0.f};
#pragma unroll
  for (int i = 0; i < 2; ++i)
#pragma unroll
    for (int j = 0; j < 2; ++j) acc[i][j] = z;
  int lin = blockIdx.x;
  int swz = (lin & 7) * 128 + (lin >> 3);  // 1024 = 8*128, bijective
  int n0 = (swz & 15) * 64, m0 = (swz >> 4) * 64;
  gemm64_mainloop(A, Bt, m0, n0, 1024, As, Bs, acc);

  const int lane = threadIdx.x & 63, wid = threadIdx.x >> 6;
  const int wr = wid >> 1, wc = wid & 1, lr = lane & 15, lg = lane >> 4;
#pragma unroll
  for (int i = 0; i < 2; ++i) {
    int m = m0 + wr * 32 + i * 16 + lr;
    float sc = scale[m >> 11];
#pragma unroll
    for (int j = 0; j < 2; ++j) {
      int nb = n0 + wc * 32 + j * 16 + lg * 4;
      float4 bv = *(const float4*)&bo[nb];
      float4 o = {(acc[i][j][0] + bv.x) * sc, (acc[i][j][1] + bv.y) * sc,
                  (acc[i][j][2] + bv.z) * sc, (acc[i][j][3] + bv.w) * sc};
      *(float4*)&out[(size_t)m * 1024 + nb] = o;
    }
  }
}

// ---------- flash attention, split-K(2), mobius transform, exp2-domain softmax ----------
// grid 2048 = [split 2][b 2][h 16][qtile 32], 256 thr = 4 waves, wave owns 16 queries.
// QK^T = mfma(kf, qf): lane&15 = query. PV = mfma(vf, pf): lane&15 = query (corr is
// lane-local), lg*4+r = d (packed stores). K LDS dbuf+swizzle; V read direct from L2;
// P per-wave LDS. Defer-max (T13, THR=8 log2), setprio (T5). Unnormalized bf16 O + (m,l).
__global__ __launch_bounds__(256, 6) void attn_kernel(
    const u16* __restrict__ Qb, const u16* __restrict__ Kb, const u16* __restrict__ Vt,
    const float* __restrict__ mobius, u16* __restrict__ O0, u16* __restrict__ O1,
    float2* __restrict__ ML) {
  __shared__ __align__(16) u16 Ks[2][64 * 64];
  __shared__ __align__(16) u16 Ps[64 * 64];  // P tile: [query][key], per-wave 16 rows
  const int tid = threadIdx.x;
  const int lane = tid & 63, w = tid >> 6;
  const int lr = lane & 15, lg = lane >> 4;
  // XCD-aware bijective swizzle (2048 = 8*256): each XCD owns 8 whole (spl,b,h) groups.
  const int bid = blockIdx.x;
  const int swz = (bid & 7) * 256 + (bid >> 3);
  const int qb = swz & 31, h = (swz >> 5) & 15, b = (swz >> 9) & 1, spl = swz >> 10;
  const float msc = mobius[h];

  const int srow = tid >> 3;                      // staging row (0..31)
  const int scol = ((tid & 7) ^ (srow & 7)) * 8;  // pre-swizzled source col (u16)
  const int rxor = (lr & 7) << 4;                 // read-side swizzle (bytes)

  // Q fragments in registers (Q pre-scaled by 1/8)
  const u16* qgl = Qb + (size_t)(b * 2048 + qb * 64 + w * 16 + lr) * 1024 + h * 64 + lg * 8;
  short8 qf0 = *(const short8*)qgl;
  short8 qf1 = *(const short8*)(qgl + 32);

  const u16* kg = Kb + ((size_t)(b * 2048 + spl * 1024 + srow)) * 1024 + h * 64 + scol;
  const u16* vbase = Vt + ((size_t)(b * 16 + h) * 64) * 2048;  // [d][s]
  // prologue: stage K tile 0 into buffer 0
  gll16(kg, Ks[0] + tid * 8);
  gll16(kg + (size_t)32 * 1024, Ks[0] + (tid + 256) * 8);

  float m_run = -3.0e38f, l_run = 0.0f;  // m in log2 domain
  f32x4 acc_o[4];
  const f32x4 z = {0.f, 0.f, 0.f, 0.f};
#pragma unroll
  for (int i = 0; i < 4; ++i) acc_o[i] = z;

  const float L2E = 1.44269504f;
  const f32x2 one2 = {1.0f, 1.0f};
  const f32x2 msc2 = {msc, msc};
  const f32x2 l2e2 = {L2E, L2E};
  const int qrow = w * 16 + lr;
  const char* Pc = (const char*)Ps;
  int cur = 0;
  for (int ktl = 0; ktl < 16; ++ktl) {
    __syncthreads();  // buffer `cur` staged; all waves done with cur^1
    if (ktl < 15) {   // stage next K tile; overlaps with compute below
      const u16* kgn = kg + (size_t)(ktl + 1) * 64 * 1024;
      u16* Kn = Ks[cur ^ 1];
      gll16(kgn, Kn + tid * 8);
      gll16(kgn + (size_t)32 * 1024, Kn + (tid + 256) * 8);
    }
    const char* Kc = (const char*)Ks[cur];

    // St = K_tile @ Q_wave^T
    f32x4 sacc[4];
#pragma unroll
    for (int i = 0; i < 4; ++i) sacc[i] = z;
    __builtin_amdgcn_s_setprio(1);
    {
      int cbx = (lg * 16) ^ rxor;
#pragma unroll
      for (int ki = 0; ki < 4; ++ki) {
        short8 kf = *(const short8*)(Kc + (ki * 16 + lr) * 128 + cbx);
        sacc[ki] = __builtin_amdgcn_mfma_f32_16x16x32_bf16(kf, qf0, sacc[ki], 0, 0, 0);
      }
      cbx = (64 + lg * 16) ^ rxor;
#pragma unroll
      for (int ki = 0; ki < 4; ++ki) {
        short8 kf = *(const short8*)(Kc + (ki * 16 + lr) * 128 + cbx);
        sacc[ki] = __builtin_amdgcn_mfma_f32_16x16x32_bf16(kf, qf1, sacc[ki], 0, 0, 0);
      }
    }
    __builtin_amdgcn_s_setprio(0);

    // mobius transform, log2 domain: tl = (s + msc*s/(1+s^2)) * log2(e)
    f32x2 p2[8];
    f32x2 mx = {-3.0e38f, -3.0e38f};
#pragma unroll
    for (int i = 0; i < 8; ++i) {
      int ki = i >> 1, jj = i & 1;
      f32x2 s = {sacc[ki][jj * 2], sacc[ki][jj * 2 + 1]};
      f32x2 d = s * s + one2;
      f32x2 rr = {__builtin_amdgcn_rcpf(d.x), __builtin_amdgcn_rcpf(d.y)};
      f32x2 tl = (msc2 * (s * rr) + s) * l2e2;
      p2[i] = tl;
      mx = __builtin_elementwise_max(mx, tl);
    }
    float tmax = fmaxf(mx.x, mx.y);
    tmax = fmaxf(tmax, __shfl_xor(tmax, 16));
    tmax = fmaxf(tmax, __shfl_xor(tmax, 32));
    // defer-max: only rescale when the running max grew by > 8 (i.e. 2^8 headroom)
    if (__any(tmax > m_run + 8.0f)) {
      float m_new = fmaxf(m_run, tmax);
      float corr = __builtin_amdgcn_exp2f(m_run - m_new);  // per-lane = per-query
      m_run = m_new;
      l_run *= corr;
#pragma unroll
      for (int di = 0; di < 4; ++di)
#pragma unroll
        for (int r = 0; r < 4; ++r) acc_o[di][r] *= corr;
    }
    f32x2 m2 = {m_run, m_run};
    f32x2 sum2 = {0.f, 0.f};
#pragma unroll
    for (int i = 0; i < 8; ++i) {
      f32x2 e = p2[i] - m2;
      f32x2 pe = {__builtin_amdgcn_exp2f(e.x), __builtin_amdgcn_exp2f(e.y)};
      p2[i] = pe;
      sum2 += pe;
    }
    float tsum = sum2.x + sum2.y;
    tsum += __shfl_xor(tsum, 16);
    tsum += __shfl_xor(tsum, 32);
    l_run += tsum;

    // write P (bf16 via cvt_pk) into this wave's private region (swizzled, 8B stores)
#pragma unroll
    for (int ki = 0; ki < 4; ++ki) {
      u32x2 pw = {cvtpk_bf16(p2[2 * ki].x, p2[2 * ki].y),
                  cvtpk_bf16(p2[2 * ki + 1].x, p2[2 * ki + 1].y)};
      *(u32x2*)(Pc + qrow * 128 + ((ki * 32 + lg * 8) ^ rxor)) = pw;
    }

    // O += V^T-frag x P-frag (V direct from global/L2; lane&15=query, lg*4+r=d)
    const u16* vk = vbase + (size_t)(spl * 1024 + ktl * 64) + (size_t)lr * 2048 + lg * 8;
    __builtin_amdgcn_s_setprio(1);
#pragma unroll
    for (int ks = 0; ks < 2; ++ks) {
      short8 pf = *(const short8*)(Pc + qrow * 128 + ((ks * 64 + lg * 16) ^ rxor));
#pragma unroll
      for (int di = 0; di < 4; ++di) {
        short8 vf = *(const short8*)(vk + (size_t)di * 16 * 2048 + ks * 32);
        acc_o[di] = __builtin_amdgcn_mfma_f32_16x16x32_bf16(vf, pf, acc_o[di], 0, 0, 0);
      }
    }
    __builtin_amdgcn_s_setprio(0);
    cur ^= 1;
  }

  // store unnormalized O partial (bf16, packed) + per-query (m, l)
  u16* Op = spl ? O1 : O0;
  size_t obase = ((size_t)(b * 2048 + qb * 64 + w * 16 + lr)) * 1024 + h * 64;
#pragma unroll
  for (int di = 0; di < 4; ++di) {
    u16x4 o = {f2bf(acc_o[di][0]), f2bf(acc_o[di][1]), f2bf(acc_o[di][2]), f2bf(acc_o[di][3])};
    *(u16x4*)&Op[obase + di * 16 + lg * 4] = o;
  }
  if (lane < 16) {
    float2 ml;
    ml.x = m_run;
    ml.y = l_run;
    ML[(((size_t)spl * 2 + b) * 16 + h) * 2048 + qb * 64 + w * 16 + lane] = ml;
  }
}

// merge the two split-K partials; in-place into O1 (= final attn buffer).
__global__ void attn_combine_kernel(const u16* __restrict__ O0, u16* __restrict__ O1,
                                    const float2* __restrict__ ML) {
  int e = blockIdx.x * 256 + threadIdx.x;  // [b 1][q 11][h 4][dquad 4] = 2^20
  int dq = e & 15;
  int h = (e >> 4) & 15;
  int q = (e >> 8) & 2047;
  int b = e >> 19;
  float2 ml0 = ML[(((size_t)0 + b) * 16 + h) * 2048 + q];
  float2 ml1 = ML[(((size_t)2 + b) * 16 + h) * 2048 + q];
  float m = fmaxf(ml0.x, ml1.x);
  float a0 = __builtin_amdgcn_exp2f(ml0.x - m);
  float a1 = __builtin_amdgcn_exp2f(ml1.x - m);
  float linv = 1.0f / (ml0.y * a0 + ml1.y * a1);
  size_t off = ((size_t)b * 2048 + q) * 1024 + h * 64 + dq * 4;
  u16x4 v0 = *(const u16x4*)&O0[off];
  u16x4 v1 = *(const u16x4*)&O1[off];
  u16x4 o;
#pragma unroll
  for (int j = 0; j < 4; ++j)
    o[j] = f2bf((bf2f(v0[j]) * a0 + bf2f(v1[j]) * a1) * linv);
  *(u16x4*)&O1[off] = o;
}

// ---------- launch ----------

extern "C" void kernel_launch(void* const* d_in, const int* in_sizes, int n_in,
                              void* d_out, int out_size, void* d_ws, size_t ws_size,
                              hipStream_t stream) {
  const float* x = (const float*)d_in[0];
  const float* Wqkv = (const float*)d_in[1];
  const float* bqkv = (const float*)d_in[2];
  const float* Wo = (const float*)d_in[3];
  const float* bo = (const float*)d_in[4];
  const float* mob = (const float*)d_in[5];
  const float* W1 = (const float*)d_in[6];
  const float* b1 = (const float*)d_in[7];
  const float* W2 = (const float*)d_in[8];
  const float* b2 = (const float*)d_in[9];
  const float* aw = (const float*)d_in[10];
  float* out = (float*)d_out;

  const size_t MB = 1024 * 1024;
  char* ws = (char*)d_ws;
  float* scale = (float*)ws;            // 2 floats
  float* ctx = (float*)(ws + 256);      // 2048 floats
  float* hbuf = (float*)(ws + 16384);   // 2x512 floats
  char* base = ws + 32768;
  u16* xbf = (u16*)base;                  // 8MB; dead after qkv -> O0 partial
  u16* wqkvT = (u16*)(base + 8 * MB);     // 6MB; dead after qkv -> ML (1MB)
  u16* woT = (u16*)(base + 14 * MB);      // 2MB
  u16* Qb = (u16*)(base + 16 * MB);       // 8MB [B,S,H,64] (pre-scaled by 1/8)
  u16* Kb = (u16*)(base + 24 * MB);       // 8MB [B,S,H,64]
  u16* Vt = (u16*)(base + 32 * MB);       // 8MB [B,H,64,S]
  u16* attn = (u16*)(base + 40 * MB);     // 8MB [B,S,D]; also O1 split partial (in-place)
  u16* O0 = xbf;                          // split-0 partial aliases xbf
  float2* ML = (float2*)wqkvT;            // [2][2][16][2048] float2 = 1MB aliases wqkvT
  // total = 32KB + 48MB (same as r3)

  hipMemsetAsync(ctx, 0, 2048 * sizeof(float), stream);
  ctx_cvt_kernel<<<256, 256, 0, stream>>>(x, ctx, xbf);
  adaptive1_kernel<<<16, 256, 0, stream>>>(ctx, W1, b1, hbuf);
  adaptive2_kernel<<<2, 256, 0, stream>>>(hbuf, W2, b2, aw, scale);
  transpose_bf16_kernel<<<dim3(96, 32), 256, 0, stream>>>(Wqkv, wqkvT, 1024, 3072);
  transpose_bf16_kernel<<<dim3(32, 32), 256, 0, stream>>>(Wo, woT, 1024, 1024);
  gemm_qkv_kernel<<<768, 256, 0, stream>>>(xbf, wqkvT, bqkv, Qb, Kb, Vt);
  attn_kernel<<<2048, 256, 0, stream>>>(Qb, Kb, Vt, mob, O0, attn, ML);
  attn_combine_kernel<<<4096, 256, 0, stream>>>(O0, attn, ML);
  gemm_out_kernel<<<1024, 256, 0, stream>>>(attn, woT, bo, scale, out);
}

// Round 6
// 264.220 us; speedup vs baseline: 1.2922x; 1.2922x over previous
//
#include <hip/hip_runtime.h>
#include <hip/hip_bf16.h>
#include <stdint.h>

typedef unsigned short u16;
typedef unsigned int u32;
typedef __attribute__((ext_vector_type(8))) short short8;   // 8 bf16 (4 VGPRs) MFMA operand
typedef __attribute__((ext_vector_type(4))) float f32x4;    // MFMA accumulator
typedef __attribute__((ext_vector_type(2))) float f32x2;    // packed-fp32 (v_pk_*) carrier
typedef __attribute__((ext_vector_type(4))) unsigned short u16x4;
typedef __attribute__((ext_vector_type(2))) unsigned int u32x2;

#define DEVFN static __device__ __forceinline__

// ---------- helpers ----------

DEVFN u16 f2bf(float f) {  // RNE float->bf16 (finite inputs)
  u32 u = __float_as_uint(f);
  u = (u + 0x7FFFu + ((u >> 16) & 1u)) >> 16;
  return (u16)u;
}

DEVFN u32 cvtpk_bf16(float lo, float hi) {  // T12: packed f32x2 -> 2xbf16 in one u32
  u32 r;
  asm("v_cvt_pk_bf16_f32 %0, %1, %2" : "=v"(r) : "v"(lo), "v"(hi));
  return r;
}

DEVFN void gll16(const void* g, void* l) {  // async global->LDS, 16B/lane
  __builtin_amdgcn_global_load_lds((const __attribute__((address_space(1))) u32*)g,
                                   (__attribute__((address_space(3))) u32*)l, 16, 0, 0);
}

// ---------- fused context-sum + bf16 convert (single pass over x) ----------
// grid 256 = [b 2][128 chunks of 16 rows]; 256 threads; thread owns 4 consecutive cols.
__global__ void ctx_cvt_kernel(const float* __restrict__ x, float* __restrict__ ctx,
                               u16* __restrict__ xbf) {
  int blk = blockIdx.x;
  int b = blk >> 7;
  int s0 = (blk & 127) * 16;
  int t = threadIdx.x;
  const float* xb = x + ((size_t)b * 2048 + s0) * 1024 + t * 4;
  u16* ob = xbf + ((size_t)b * 2048 + s0) * 1024 + t * 4;
  float4 sum = {0.f, 0.f, 0.f, 0.f};
#pragma unroll
  for (int s = 0; s < 16; ++s) {
    float4 v = *(const float4*)(xb + (size_t)s * 1024);
    sum.x += v.x;
    sum.y += v.y;
    sum.z += v.z;
    sum.w += v.w;
    u16x4 o = {f2bf(v.x), f2bf(v.y), f2bf(v.z), f2bf(v.w)};
    *(u16x4*)(ob + (size_t)s * 1024) = o;
  }
  float* c = ctx + b * 1024 + t * 4;
  atomicAdd(c + 0, sum.x);
  atomicAdd(c + 1, sum.y);
  atomicAdd(c + 2, sum.z);
  atomicAdd(c + 3, sum.w);
}

// stage 1: h = gelu(ctx/2048 @ W1 + b1). grid 32 = [b 2][jq 16 chunks of 32 j];
// 256 thr = 8 d-parts x 32 j.
__global__ void adaptive1_kernel(const float* __restrict__ ctx, const float* __restrict__ W1,
                                 const float* __restrict__ b1, float* __restrict__ hbuf) {
  int b = blockIdx.x >> 4, jq = blockIdx.x & 15;
  int t = threadIdx.x;
  int jl = t & 31, dp = t >> 5;
  int j = jq * 32 + jl;
  __shared__ float ctxs[1024];
  __shared__ float partial[8][32];
  for (int i = t; i < 1024; i += 256) ctxs[i] = ctx[b * 1024 + i] * (1.0f / 2048.0f);
  __syncthreads();
  float a0 = 0.f, a1 = 0.f;
  int d0 = dp * 128;
  for (int d = d0; d < d0 + 128; d += 2) {
    a0 += ctxs[d] * W1[(size_t)d * 512 + j];
    a1 += ctxs[d + 1] * W1[(size_t)(d + 1) * 512 + j];
  }
  partial[dp][jl] = a0 + a1;
  __syncthreads();
  if (t < 32) {
    float acc = b1[jq * 32 + t];
#pragma unroll
    for (int p = 0; p < 8; ++p) acc += partial[p][t];
    hbuf[b * 512 + jq * 32 + t] =
        0.5f * acc * (1.0f + erff(acc * 0.70710678118654752f));  // exact gelu
  }
}

// stage 2: af = sigmoid(h @ W2 + b2); scale[b] = 1 + aw*mean(af). grid 2.
__global__ void adaptive2_kernel(const float* __restrict__ hbuf, const float* __restrict__ W2,
                                 const float* __restrict__ b2, const float* __restrict__ aw,
                                 float* __restrict__ scale) {
  int b = blockIdx.x;
  int t = threadIdx.x;
  __shared__ float part[256];
  int o = t & 15, seg = t >> 4;  // 16 segs x 32 j's
  float a = 0.f;
  for (int j = seg * 32; j < seg * 32 + 32; ++j) a += hbuf[b * 512 + j] * W2[(size_t)j * 16 + o];
  part[t] = a;
  __syncthreads();
  if (t < 16) {
    float acc = b2[t];
    for (int s2 = 0; s2 < 16; ++s2) acc += part[s2 * 16 + t];
    part[t] = 1.0f / (1.0f + __expf(-acc));
  }
  __syncthreads();
  if (t == 0) {
    float s = 0.f;
    for (int i = 0; i < 16; ++i) s += part[i];
    scale[b] = 1.0f + aw[0] * (s * (1.0f / 16.0f));
  }
}

// in: fp32 [K][N] row-major -> out: bf16 [N][K] row-major. grid (N/32, K/32), 256 thr.
__global__ void transpose_bf16_kernel(const float* __restrict__ in, u16* __restrict__ out,
                                      int K, int N) {
  __shared__ u16 tile[32][33];
  int n0 = blockIdx.x * 32, k0 = blockIdx.y * 32;
  int tc = threadIdx.x & 31, tr = threadIdx.x >> 5;  // tr in 0..7
  for (int i = tr; i < 32; i += 8)
    tile[i][tc] = f2bf(in[(size_t)(k0 + i) * N + n0 + tc]);
  __syncthreads();
  for (int i = tr; i < 32; i += 8)
    out[(size_t)(n0 + i) * K + k0 + tc] = tile[tc][i];
}

// ---------- GEMM mainloops: swizzled LDS + 2-phase double-buffer ----------
// C = A(MxK bf16 rowmajor) @ Bt(NxK bf16 rowmajor)^T, fp32 acc. K multiple of 32.
// acc[i][j] = mfma(bf[j], af[i]) -> lane&15 = m-row (i*16+lr), lg*4+r = n-col (j*16+lg*4+r):
// each lane owns 4 CONSECUTIVE output columns -> packed epilogue stores.

// 128x128 tile, 4 waves. As/Bs are [2][128*32] u16.
DEVFN void gemm_tile_mainloop(const u16* __restrict__ A, const u16* __restrict__ Bt,
                              int m0, int n0, int K, u16* As, u16* Bs, f32x4 acc[4][4]) {
  const int tid = threadIdx.x;
  const int lane = tid & 63, wid = tid >> 6;
  const int wr = wid >> 1, wc = wid & 1;
  const int lr = lane & 15, lg = lane >> 4;
  const int srow = tid >> 2;
  const int scol = ((tid & 3) ^ ((tid >> 3) & 3)) * 8;  // pre-swizzled source col (u16)
  const int axor = ((lr >> 1) & 3) << 4;                // read-side swizzle (bytes)

  const u16* ag0 = A + (size_t)(m0 + srow) * K + scol;
  const u16* ag1 = ag0 + (size_t)64 * K;
  const u16* bg0 = Bt + (size_t)(n0 + srow) * K + scol;
  const u16* bg1 = bg0 + (size_t)64 * K;

  // prologue: stage K-step 0 into buffer 0
  gll16(ag0, As + tid * 8);
  gll16(ag1, As + (tid + 256) * 8);
  gll16(bg0, Bs + tid * 8);
  gll16(bg1, Bs + (tid + 256) * 8);

  int cur = 0;
  for (int k0 = 0; k0 < K; k0 += 32) {
    __syncthreads();    // drains vmcnt: buffer `cur` staged & prev compute on cur^1 done
    if (k0 + 32 < K) {  // issue next-step stage; overlaps with compute below
      int nb = (cur ^ 1) * 4096;
      gll16(ag0 + k0 + 32, As + nb + tid * 8);
      gll16(ag1 + k0 + 32, As + nb + (tid + 256) * 8);
      gll16(bg0 + k0 + 32, Bs + nb + tid * 8);
      gll16(bg1 + k0 + 32, Bs + nb + (tid + 256) * 8);
    }
    const char* Ac = (const char*)(As + cur * 4096);
    const char* Bc = (const char*)(Bs + cur * 4096);
    short8 af[4], bf[4];
#pragma unroll
    for (int i = 0; i < 4; ++i)
      af[i] = *(const short8*)(Ac + (wr * 64 + i * 16 + lr) * 64 + ((lg * 16) ^ axor));
#pragma unroll
    for (int j = 0; j < 4; ++j)
      bf[j] = *(const short8*)(Bc + (wc * 64 + j * 16 + lr) * 64 + ((lg * 16) ^ axor));
#pragma unroll
    for (int i = 0; i < 4; ++i)
#pragma unroll
      for (int j = 0; j < 4; ++j)
        acc[i][j] = __builtin_amdgcn_mfma_f32_16x16x32_bf16(bf[j], af[i], acc[i][j], 0, 0, 0);
    cur ^= 1;
  }
}

// 64x64 tile, 4 waves (for skinny GEMM2). As/Bs are [2][64*32] u16.
DEVFN void gemm64_mainloop(const u16* __restrict__ A, const u16* __restrict__ Bt,
                           int m0, int n0, int K, u16* As, u16* Bs, f32x4 acc[2][2]) {
  const int tid = threadIdx.x;
  const int lane = tid & 63, wid = tid >> 6;
  const int wr = wid >> 1, wc = wid & 1;
  const int lr = lane & 15, lg = lane >> 4;
  const int srow = tid >> 2;
  const int scol = ((tid & 3) ^ ((tid >> 3) & 3)) * 8;
  const int axor = ((lr >> 1) & 3) << 4;

  const u16* ag = A + (size_t)(m0 + srow) * K + scol;
  const u16* bg = Bt + (size_t)(n0 + srow) * K + scol;
  gll16(ag, As + tid * 8);
  gll16(bg, Bs + tid * 8);

  int cur = 0;
  for (int k0 = 0; k0 < K; k0 += 32) {
    __syncthreads();
    if (k0 + 32 < K) {
      int nb = (cur ^ 1) * 2048;
      gll16(ag + k0 + 32, As + nb + tid * 8);
      gll16(bg + k0 + 32, Bs + nb + tid * 8);
    }
    const char* Ac = (const char*)(As + cur * 2048);
    const char* Bc = (const char*)(Bs + cur * 2048);
    short8 af[2], bf[2];
#pragma unroll
    for (int i = 0; i < 2; ++i)
      af[i] = *(const short8*)(Ac + (wr * 32 + i * 16 + lr) * 64 + ((lg * 16) ^ axor));
#pragma unroll
    for (int j = 0; j < 2; ++j)
      bf[j] = *(const short8*)(Bc + (wc * 32 + j * 16 + lr) * 64 + ((lg * 16) ^ axor));
#pragma unroll
    for (int i = 0; i < 2; ++i)
#pragma unroll
      for (int j = 0; j < 2; ++j)
        acc[i][j] = __builtin_amdgcn_mfma_f32_16x16x32_bf16(bf[j], af[i], acc[i][j], 0, 0, 0);
    cur ^= 1;
  }
}

// GEMM1: qkv = x_bf16 @ WqkvT^T + bqkv -> Q[b,s,h,d] (pre-scaled 1/8), K[b,s,h,d],
// V^T[b,h,d,s]. grid 768 1-D with XCD swizzle.
__global__ __launch_bounds__(256) void gemm_qkv_kernel(
    const u16* __restrict__ A, const u16* __restrict__ Bt, const float* __restrict__ bias,
    u16* __restrict__ Qb, u16* __restrict__ Kb, u16* __restrict__ Vt) {
  __shared__ __align__(16) u16 As[2 * 128 * 32];
  __shared__ __align__(16) u16 Bs[2 * 128 * 32];
  f32x4 acc[4][4];
  const f32x4 z = {0.f, 0.f, 0.f, 0.f};
#pragma unroll
  for (int i = 0; i < 4; ++i)
#pragma unroll
    for (int j = 0; j < 4; ++j) acc[i][j] = z;
  int lin = blockIdx.x;
  int swz = (lin & 7) * 96 + (lin >> 3);  // 768 = 8*96, bijective
  int n0 = (swz % 24) * 128, m0 = (swz / 24) * 128;
  gemm_tile_mainloop(A, Bt, m0, n0, 1024, As, Bs, acc);

  const int lane = threadIdx.x & 63, wid = threadIdx.x >> 6;
  const int wr = wid >> 1, wc = wid & 1, lr = lane & 15, lg = lane >> 4;
#pragma unroll
  for (int i = 0; i < 4; ++i) {
    int m = m0 + wr * 64 + i * 16 + lr;  // token row
#pragma unroll
    for (int j = 0; j < 4; ++j) {
      int nb = n0 + wc * 64 + j * 16 + lg * 4;  // col base, +r consecutive
      float4 bv = *(const float4*)&bias[nb];
      int c3 = nb >> 10;
      if (c3 == 2) {  // V^T: 4 consecutive d at fixed s -> scalar stores
        int bb = m >> 11, ss = m & 2047;
        int hh = (nb >> 6) & 15, dd = nb & 63;
        size_t vb_ = (((size_t)bb * 16 + hh) * 64 + dd) * 2048 + ss;
        Vt[vb_] = f2bf(acc[i][j][0] + bv.x);
        Vt[vb_ + 2048] = f2bf(acc[i][j][1] + bv.y);
        Vt[vb_ + 4096] = f2bf(acc[i][j][2] + bv.z);
        Vt[vb_ + 6144] = f2bf(acc[i][j][3] + bv.w);
      } else {
        u16* dst = (c3 == 0) ? Qb : Kb;
        float qs = (c3 == 0) ? 0.125f : 1.0f;  // fold 1/sqrt(dh) into Q
        u16x4 o = {f2bf((acc[i][j][0] + bv.x) * qs), f2bf((acc[i][j][1] + bv.y) * qs),
                   f2bf((acc[i][j][2] + bv.z) * qs), f2bf((acc[i][j][3] + bv.w) * qs)};
        *(u16x4*)&dst[(size_t)m * 1024 + (nb & 1023)] = o;
      }
    }
  }
}

// GEMM2: out = (attn_bf16 @ WoT^T + bo) * scale[b], fp32 out. 64x64 tiles, grid 1024 1-D.
__global__ __launch_bounds__(256) void gemm_out_kernel(
    const u16* __restrict__ A, const u16* __restrict__ Bt, const float* __restrict__ bo,
    const float* __restrict__ scale, float* __restrict__ out) {
  __shared__ __align__(16) u16 As[2 * 64 * 32];
  __shared__ __align__(16) u16 Bs[2 * 64 * 32];
  f32x4 acc[2][2];
  const f32x4 z = {0.f, 0.f, 0.f, 0.f};
#pragma unroll
  for (int i = 0; i < 2; ++i)
#pragma unroll
    for (int j = 0; j < 2; ++j) acc[i][j] = z;
  int lin = blockIdx.x;
  int swz = (lin & 7) * 128 + (lin >> 3);  // 1024 = 8*128, bijective
  int n0 = (swz & 15) * 64, m0 = (swz >> 4) * 64;
  gemm64_mainloop(A, Bt, m0, n0, 1024, As, Bs, acc);

  const int lane = threadIdx.x & 63, wid = threadIdx.x >> 6;
  const int wr = wid >> 1, wc = wid & 1, lr = lane & 15, lg = lane >> 4;
#pragma unroll
  for (int i = 0; i < 2; ++i) {
    int m = m0 + wr * 32 + i * 16 + lr;
    float sc = scale[m >> 11];
#pragma unroll
    for (int j = 0; j < 2; ++j) {
      int nb = n0 + wc * 32 + j * 16 + lg * 4;
      float4 bv = *(const float4*)&bo[nb];
      float4 o = {(acc[i][j][0] + bv.x) * sc, (acc[i][j][1] + bv.y) * sc,
                  (acc[i][j][2] + bv.z) * sc, (acc[i][j][3] + bv.w) * sc};
      *(float4*)&out[(size_t)m * 1024 + nb] = o;
    }
  }
}

// ---------- flash attention with mobius score transform ----------
// grid 1024 = [b 2][h 16][qtile 32], 256 thr = 4 waves, wave owns 16 queries.
// QK^T = mfma(kf, qf): sacc col = query = lane&15, row = key = 16ki+lg*4+r.
// PV  = mfma(vf, pf): acc_o col = query = lane&15 (corr/linv LANE-LOCAL, no shuffles),
// row = d = lg*4+r (packed u16x4 O-stores). K/V in LDS (dbuf, XOR-swizzled, gll16-staged);
// P per-wave LDS. exp2-domain softmax, pk-f32 math, rcp, cvt_pk (T12), defer-max (T13),
// setprio (T5).
__global__ __launch_bounds__(256) void attn_kernel(
    const u16* __restrict__ Qb, const u16* __restrict__ Kb, const u16* __restrict__ Vt,
    const float* __restrict__ mobius, u16* __restrict__ O) {
  __shared__ __align__(16) u16 Ks[2][64 * 64];
  __shared__ __align__(16) u16 Vs[2][64 * 64];  // V^T tile: [d][key]
  __shared__ __align__(16) u16 Ps[64 * 64];     // P tile: [query][key], per-wave 16 rows
  const int tid = threadIdx.x;
  const int lane = tid & 63, w = tid >> 6;
  const int lr = lane & 15, lg = lane >> 4;
  // XCD-aware bijective swizzle (1024 = 8*128): each XCD owns 4 whole (b,h) groups.
  const int bid = blockIdx.x;
  const int bidx = (bid & 7) * 128 + (bid >> 3);
  const int qb = bidx & 31, h = (bidx >> 5) & 15, b = bidx >> 9;
  const float msc = mobius[h];

  const int srow = tid >> 3;                      // staging row (0..31)
  const int scol = ((tid & 7) ^ (srow & 7)) * 8;  // pre-swizzled source col (u16)
  const int rxor = (lr & 7) << 4;                 // read-side swizzle (bytes)

  // Q fragments in registers (Q pre-scaled by 1/8)
  const u16* qgl = Qb + (size_t)(b * 2048 + qb * 64 + w * 16 + lr) * 1024 + h * 64 + lg * 8;
  short8 qf0 = *(const short8*)qgl;
  short8 qf1 = *(const short8*)(qgl + 32);

  const u16* kg = Kb + (size_t)(b * 2048 + srow) * 1024 + h * 64 + scol;
  const u16* vg = Vt + ((size_t)(b * 16 + h) * 64 + srow) * 2048 + scol;

  // prologue: stage K/V tile 0 into buffer 0
  gll16(kg, Ks[0] + tid * 8);
  gll16(kg + (size_t)32 * 1024, Ks[0] + (tid + 256) * 8);
  gll16(vg, Vs[0] + tid * 8);
  gll16(vg + 32 * 2048, Vs[0] + (tid + 256) * 8);

  float m_run = -3.0e38f, l_run = 0.0f;  // m in log2 domain
  f32x4 acc_o[4];
  const f32x4 z = {0.f, 0.f, 0.f, 0.f};
#pragma unroll
  for (int i = 0; i < 4; ++i) acc_o[i] = z;

  const float L2E = 1.44269504f;
  const f32x2 one2 = {1.0f, 1.0f};
  const f32x2 msc2 = {msc, msc};
  const f32x2 l2e2 = {L2E, L2E};
  const int qrow = w * 16 + lr;
  const char* Pc = (const char*)Ps;
  int cur = 0;
  for (int kt = 0; kt < 32; ++kt) {
    __syncthreads();  // buffer `cur` staged; all waves done with cur^1
    if (kt < 31) {    // stage next K/V tile; overlaps with compute below
      const u16* kgn = kg + (size_t)(kt + 1) * 64 * 1024;
      const u16* vgn = vg + (kt + 1) * 64;
      u16* Kn = Ks[cur ^ 1];
      u16* Vn = Vs[cur ^ 1];
      gll16(kgn, Kn + tid * 8);
      gll16(kgn + (size_t)32 * 1024, Kn + (tid + 256) * 8);
      gll16(vgn, Vn + tid * 8);
      gll16(vgn + 32 * 2048, Vn + (tid + 256) * 8);
    }
    const char* Kc = (const char*)Ks[cur];
    const char* Vc = (const char*)Vs[cur];

    // St = K_tile @ Q_wave^T
    f32x4 sacc[4];
#pragma unroll
    for (int i = 0; i < 4; ++i) sacc[i] = z;
    __builtin_amdgcn_s_setprio(1);
    {
      int cbx = (lg * 16) ^ rxor;
#pragma unroll
      for (int ki = 0; ki < 4; ++ki) {
        short8 kf = *(const short8*)(Kc + (ki * 16 + lr) * 128 + cbx);
        sacc[ki] = __builtin_amdgcn_mfma_f32_16x16x32_bf16(kf, qf0, sacc[ki], 0, 0, 0);
      }
      cbx = (64 + lg * 16) ^ rxor;
#pragma unroll
      for (int ki = 0; ki < 4; ++ki) {
        short8 kf = *(const short8*)(Kc + (ki * 16 + lr) * 128 + cbx);
        sacc[ki] = __builtin_amdgcn_mfma_f32_16x16x32_bf16(kf, qf1, sacc[ki], 0, 0, 0);
      }
    }
    __builtin_amdgcn_s_setprio(0);

    // mobius transform, log2 domain: tl = (s + msc*s/(1+s^2)) * log2(e)
    f32x2 p2[8];
    f32x2 mx = {-3.0e38f, -3.0e38f};
#pragma unroll
    for (int i = 0; i < 8; ++i) {
      int ki = i >> 1, jj = i & 1;
      f32x2 s = {sacc[ki][jj * 2], sacc[ki][jj * 2 + 1]};
      f32x2 d = s * s + one2;
      f32x2 rr = {__builtin_amdgcn_rcpf(d.x), __builtin_amdgcn_rcpf(d.y)};
      f32x2 tl = (msc2 * (s * rr) + s) * l2e2;
      p2[i] = tl;
      mx = __builtin_elementwise_max(mx, tl);
    }
    float tmax = fmaxf(mx.x, mx.y);
    tmax = fmaxf(tmax, __shfl_xor(tmax, 16));
    tmax = fmaxf(tmax, __shfl_xor(tmax, 32));
    // defer-max: only rescale when the running max grew by > 8 (2^8 headroom in P)
    if (__any(tmax > m_run + 8.0f)) {
      float m_new = fmaxf(m_run, tmax);
      float corr = __builtin_amdgcn_exp2f(m_run - m_new);  // per-lane = per-query
      m_run = m_new;
      l_run *= corr;
#pragma unroll
      for (int di = 0; di < 4; ++di)
#pragma unroll
        for (int r = 0; r < 4; ++r) acc_o[di][r] *= corr;
    }
    f32x2 m2 = {m_run, m_run};
    f32x2 sum2 = {0.f, 0.f};
#pragma unroll
    for (int i = 0; i < 8; ++i) {
      f32x2 e = p2[i] - m2;
      f32x2 pe = {__builtin_amdgcn_exp2f(e.x), __builtin_amdgcn_exp2f(e.y)};
      p2[i] = pe;
      sum2 += pe;
    }
    float tsum = sum2.x + sum2.y;
    tsum += __shfl_xor(tsum, 16);
    tsum += __shfl_xor(tsum, 32);
    l_run += tsum;

    // write P (bf16 via cvt_pk) into this wave's private region (swizzled, 8B stores)
#pragma unroll
    for (int ki = 0; ki < 4; ++ki) {
      u32x2 pw = {cvtpk_bf16(p2[2 * ki].x, p2[2 * ki].y),
                  cvtpk_bf16(p2[2 * ki + 1].x, p2[2 * ki + 1].y)};
      *(u32x2*)(Pc + qrow * 128 + ((ki * 32 + lg * 8) ^ rxor)) = pw;
    }

    // O += V^T-frag x P-frag (both from LDS; col=query lane-local, row=d packed)
    __builtin_amdgcn_s_setprio(1);
#pragma unroll
    for (int ks = 0; ks < 2; ++ks) {
      int cbx = (ks * 64 + lg * 16) ^ rxor;
      short8 pf = *(const short8*)(Pc + qrow * 128 + cbx);
#pragma unroll
      for (int di = 0; di < 4; ++di) {
        short8 vf = *(const short8*)(Vc + (di * 16 + lr) * 128 + cbx);
        acc_o[di] = __builtin_amdgcn_mfma_f32_16x16x32_bf16(vf, pf, acc_o[di], 0, 0, 0);
      }
    }
    __builtin_amdgcn_s_setprio(0);
    cur ^= 1;
  }

  // normalized bf16 O, packed 8B stores; linv lane-local (q = lane&15)
  float linv = 1.0f / l_run;
  size_t obase = ((size_t)(b * 2048 + qb * 64 + w * 16 + lr)) * 1024 + h * 64;
#pragma unroll
  for (int di = 0; di < 4; ++di) {
    u32x2 o = {cvtpk_bf16(acc_o[di][0] * linv, acc_o[di][1] * linv),
               cvtpk_bf16(acc_o[di][2] * linv, acc_o[di][3] * linv)};
    *(u32x2*)&O[obase + di * 16 + lg * 4] = o;
  }
}

// ---------- launch ----------

extern "C" void kernel_launch(void* const* d_in, const int* in_sizes, int n_in,
                              void* d_out, int out_size, void* d_ws, size_t ws_size,
                              hipStream_t stream) {
  const float* x = (const float*)d_in[0];
  const float* Wqkv = (const float*)d_in[1];
  const float* bqkv = (const float*)d_in[2];
  const float* Wo = (const float*)d_in[3];
  const float* bo = (const float*)d_in[4];
  const float* mob = (const float*)d_in[5];
  const float* W1 = (const float*)d_in[6];
  const float* b1 = (const float*)d_in[7];
  const float* W2 = (const float*)d_in[8];
  const float* b2 = (const float*)d_in[9];
  const float* aw = (const float*)d_in[10];
  float* out = (float*)d_out;

  const size_t MB = 1024 * 1024;
  char* ws = (char*)d_ws;
  float* scale = (float*)ws;           // 2 floats
  float* ctx = (float*)(ws + 256);     // 2048 floats
  float* hbuf = (float*)(ws + 16384);  // 2x512 floats
  char* base = ws + 32768;
  u16* xbf = (u16*)base;               // 8MB
  u16* wqkvT = (u16*)(base + 8 * MB);  // 6MB
  u16* woT = (u16*)(base + 14 * MB);   // 2MB
  u16* Qb = (u16*)(base + 16 * MB);    // 8MB [B,S,H,64] (pre-scaled by 1/8)
  u16* Kb = (u16*)(base + 24 * MB);    // 8MB [B,S,H,64]
  u16* Vt = (u16*)(base + 32 * MB);    // 8MB [B,H,64,S]
  u16* attn = (u16*)(base + 40 * MB);  // 8MB [B,S,D]
  // total = 32KB + 48MB

  hipMemsetAsync(ctx, 0, 2048 * sizeof(float), stream);
  ctx_cvt_kernel<<<256, 256, 0, stream>>>(x, ctx, xbf);
  adaptive1_kernel<<<32, 256, 0, stream>>>(ctx, W1, b1, hbuf);
  adaptive2_kernel<<<2, 256, 0, stream>>>(hbuf, W2, b2, aw, scale);
  transpose_bf16_kernel<<<dim3(96, 32), 256, 0, stream>>>(Wqkv, wqkvT, 1024, 3072);
  transpose_bf16_kernel<<<dim3(32, 32), 256, 0, stream>>>(Wo, woT, 1024, 1024);
  gemm_qkv_kernel<<<768, 256, 0, stream>>>(xbf, wqkvT, bqkv, Qb, Kb, Vt);
  attn_kernel<<<1024, 256, 0, stream>>>(Qb, Kb, Vt, mob, attn);
  gemm_out_kernel<<<1024, 256, 0, stream>>>(attn, woT, bo, scale, out);
}

// Round 7
// 260.014 us; speedup vs baseline: 1.3131x; 1.0162x over previous
//
#include <hip/hip_runtime.h>
#include <hip/hip_bf16.h>
#include <stdint.h>

typedef unsigned short u16;
typedef unsigned int u32;
typedef __attribute__((ext_vector_type(8))) short short8;   // 8 bf16 (4 VGPRs) MFMA operand
typedef __attribute__((ext_vector_type(4))) float f32x4;    // MFMA accumulator
typedef __attribute__((ext_vector_type(2))) float f32x2;    // packed-fp32 (v_pk_*) carrier
typedef __attribute__((ext_vector_type(4))) unsigned short u16x4;
typedef __attribute__((ext_vector_type(2))) unsigned int u32x2;

#define DEVFN static __device__ __forceinline__

// ---------- helpers ----------

DEVFN u16 f2bf(float f) {  // RNE float->bf16 (finite inputs)
  u32 u = __float_as_uint(f);
  u = (u + 0x7FFFu + ((u >> 16) & 1u)) >> 16;
  return (u16)u;
}

DEVFN u32 cvtpk_bf16(float lo, float hi) {  // T12: packed f32x2 -> 2xbf16 in one u32
  u32 r;
  asm("v_cvt_pk_bf16_f32 %0, %1, %2" : "=v"(r) : "v"(lo), "v"(hi));
  return r;
}

DEVFN void gll16(const void* g, void* l) {  // async global->LDS, 16B/lane
  __builtin_amdgcn_global_load_lds((const __attribute__((address_space(1))) u32*)g,
                                   (__attribute__((address_space(3))) u32*)l, 16, 0, 0);
}

// ---------- fused context-sum + bf16 convert (single pass over x) ----------
// grid 256 = [b 2][128 chunks of 16 rows]; 256 threads; thread owns 4 consecutive cols.
__global__ void ctx_cvt_kernel(const float* __restrict__ x, float* __restrict__ ctx,
                               u16* __restrict__ xbf) {
  int blk = blockIdx.x;
  int b = blk >> 7;
  int s0 = (blk & 127) * 16;
  int t = threadIdx.x;
  const float* xb = x + ((size_t)b * 2048 + s0) * 1024 + t * 4;
  u16* ob = xbf + ((size_t)b * 2048 + s0) * 1024 + t * 4;
  float4 sum = {0.f, 0.f, 0.f, 0.f};
#pragma unroll
  for (int s = 0; s < 16; ++s) {
    float4 v = *(const float4*)(xb + (size_t)s * 1024);
    sum.x += v.x;
    sum.y += v.y;
    sum.z += v.z;
    sum.w += v.w;
    u16x4 o = {f2bf(v.x), f2bf(v.y), f2bf(v.z), f2bf(v.w)};
    *(u16x4*)(ob + (size_t)s * 1024) = o;
  }
  float* c = ctx + b * 1024 + t * 4;
  atomicAdd(c + 0, sum.x);
  atomicAdd(c + 1, sum.y);
  atomicAdd(c + 2, sum.z);
  atomicAdd(c + 3, sum.w);
}

// stage 1: h = gelu(ctx/2048 @ W1 + b1). grid 32 = [b 2][jq 16 chunks of 32 j];
// 256 thr = 8 d-parts x 32 j.
__global__ void adaptive1_kernel(const float* __restrict__ ctx, const float* __restrict__ W1,
                                 const float* __restrict__ b1, float* __restrict__ hbuf) {
  int b = blockIdx.x >> 4, jq = blockIdx.x & 15;
  int t = threadIdx.x;
  int jl = t & 31, dp = t >> 5;
  int j = jq * 32 + jl;
  __shared__ float ctxs[1024];
  __shared__ float partial[8][32];
  for (int i = t; i < 1024; i += 256) ctxs[i] = ctx[b * 1024 + i] * (1.0f / 2048.0f);
  __syncthreads();
  float a0 = 0.f, a1 = 0.f;
  int d0 = dp * 128;
  for (int d = d0; d < d0 + 128; d += 2) {
    a0 += ctxs[d] * W1[(size_t)d * 512 + j];
    a1 += ctxs[d + 1] * W1[(size_t)(d + 1) * 512 + j];
  }
  partial[dp][jl] = a0 + a1;
  __syncthreads();
  if (t < 32) {
    float acc = b1[jq * 32 + t];
#pragma unroll
    for (int p = 0; p < 8; ++p) acc += partial[p][t];
    hbuf[b * 512 + jq * 32 + t] =
        0.5f * acc * (1.0f + erff(acc * 0.70710678118654752f));  // exact gelu
  }
}

// stage 2: af = sigmoid(h @ W2 + b2); scale[b] = 1 + aw*mean(af). grid 2.
__global__ void adaptive2_kernel(const float* __restrict__ hbuf, const float* __restrict__ W2,
                                 const float* __restrict__ b2, const float* __restrict__ aw,
                                 float* __restrict__ scale) {
  int b = blockIdx.x;
  int t = threadIdx.x;
  __shared__ float part[256];
  int o = t & 15, seg = t >> 4;  // 16 segs x 32 j's
  float a = 0.f;
  for (int j = seg * 32; j < seg * 32 + 32; ++j) a += hbuf[b * 512 + j] * W2[(size_t)j * 16 + o];
  part[t] = a;
  __syncthreads();
  if (t < 16) {
    float acc = b2[t];
    for (int s2 = 0; s2 < 16; ++s2) acc += part[s2 * 16 + t];
    part[t] = 1.0f / (1.0f + __expf(-acc));
  }
  __syncthreads();
  if (t == 0) {
    float s = 0.f;
    for (int i = 0; i < 16; ++i) s += part[i];
    scale[b] = 1.0f + aw[0] * (s * (1.0f / 16.0f));
  }
}

// in: fp32 [K][N] row-major -> out: bf16 [N][K] row-major. grid (N/32, K/32), 256 thr.
__global__ void transpose_bf16_kernel(const float* __restrict__ in, u16* __restrict__ out,
                                      int K, int N) {
  __shared__ u16 tile[32][33];
  int n0 = blockIdx.x * 32, k0 = blockIdx.y * 32;
  int tc = threadIdx.x & 31, tr = threadIdx.x >> 5;  // tr in 0..7
  for (int i = tr; i < 32; i += 8)
    tile[i][tc] = f2bf(in[(size_t)(k0 + i) * N + n0 + tc]);
  __syncthreads();
  for (int i = tr; i < 32; i += 8)
    out[(size_t)(n0 + i) * K + k0 + tc] = tile[tc][i];
}

// ---------- GEMM mainloops: swizzled LDS + 2-phase double-buffer ----------
// C = A(MxK bf16 rowmajor) @ Bt(NxK bf16 rowmajor)^T, fp32 acc. K multiple of 32.
// acc[i][j] = mfma(bf[j], af[i]) -> lane&15 = m-row (i*16+lr), lg*4+r = n-col (j*16+lg*4+r):
// each lane owns 4 CONSECUTIVE output columns -> packed epilogue stores.

// 128x128 tile, 4 waves. As/Bs are [2][128*32] u16.
DEVFN void gemm_tile_mainloop(const u16* __restrict__ A, const u16* __restrict__ Bt,
                              int m0, int n0, int K, u16* As, u16* Bs, f32x4 acc[4][4]) {
  const int tid = threadIdx.x;
  const int lane = tid & 63, wid = tid >> 6;
  const int wr = wid >> 1, wc = wid & 1;
  const int lr = lane & 15, lg = lane >> 4;
  const int srow = tid >> 2;
  const int scol = ((tid & 3) ^ ((tid >> 3) & 3)) * 8;  // pre-swizzled source col (u16)
  const int axor = ((lr >> 1) & 3) << 4;                // read-side swizzle (bytes)

  const u16* ag0 = A + (size_t)(m0 + srow) * K + scol;
  const u16* ag1 = ag0 + (size_t)64 * K;
  const u16* bg0 = Bt + (size_t)(n0 + srow) * K + scol;
  const u16* bg1 = bg0 + (size_t)64 * K;

  // prologue: stage K-step 0 into buffer 0
  gll16(ag0, As + tid * 8);
  gll16(ag1, As + (tid + 256) * 8);
  gll16(bg0, Bs + tid * 8);
  gll16(bg1, Bs + (tid + 256) * 8);

  int cur = 0;
  for (int k0 = 0; k0 < K; k0 += 32) {
    __syncthreads();    // drains vmcnt: buffer `cur` staged & prev compute on cur^1 done
    if (k0 + 32 < K) {  // issue next-step stage; overlaps with compute below
      int nb = (cur ^ 1) * 4096;
      gll16(ag0 + k0 + 32, As + nb + tid * 8);
      gll16(ag1 + k0 + 32, As + nb + (tid + 256) * 8);
      gll16(bg0 + k0 + 32, Bs + nb + tid * 8);
      gll16(bg1 + k0 + 32, Bs + nb + (tid + 256) * 8);
    }
    const char* Ac = (const char*)(As + cur * 4096);
    const char* Bc = (const char*)(Bs + cur * 4096);
    short8 af[4], bf[4];
#pragma unroll
    for (int i = 0; i < 4; ++i)
      af[i] = *(const short8*)(Ac + (wr * 64 + i * 16 + lr) * 64 + ((lg * 16) ^ axor));
#pragma unroll
    for (int j = 0; j < 4; ++j)
      bf[j] = *(const short8*)(Bc + (wc * 64 + j * 16 + lr) * 64 + ((lg * 16) ^ axor));
#pragma unroll
    for (int i = 0; i < 4; ++i)
#pragma unroll
      for (int j = 0; j < 4; ++j)
        acc[i][j] = __builtin_amdgcn_mfma_f32_16x16x32_bf16(bf[j], af[i], acc[i][j], 0, 0, 0);
    cur ^= 1;
  }
}

// 64x64 tile, 4 waves (for skinny GEMM2). As/Bs are [2][64*32] u16.
DEVFN void gemm64_mainloop(const u16* __restrict__ A, const u16* __restrict__ Bt,
                           int m0, int n0, int K, u16* As, u16* Bs, f32x4 acc[2][2]) {
  const int tid = threadIdx.x;
  const int lane = tid & 63, wid = tid >> 6;
  const int wr = wid >> 1, wc = wid & 1;
  const int lr = lane & 15, lg = lane >> 4;
  const int srow = tid >> 2;
  const int scol = ((tid & 3) ^ ((tid >> 3) & 3)) * 8;
  const int axor = ((lr >> 1) & 3) << 4;

  const u16* ag = A + (size_t)(m0 + srow) * K + scol;
  const u16* bg = Bt + (size_t)(n0 + srow) * K + scol;
  gll16(ag, As + tid * 8);
  gll16(bg, Bs + tid * 8);

  int cur = 0;
  for (int k0 = 0; k0 < K; k0 += 32) {
    __syncthreads();
    if (k0 + 32 < K) {
      int nb = (cur ^ 1) * 2048;
      gll16(ag + k0 + 32, As + nb + tid * 8);
      gll16(bg + k0 + 32, Bs + nb + tid * 8);
    }
    const char* Ac = (const char*)(As + cur * 2048);
    const char* Bc = (const char*)(Bs + cur * 2048);
    short8 af[2], bf[2];
#pragma unroll
    for (int i = 0; i < 2; ++i)
      af[i] = *(const short8*)(Ac + (wr * 32 + i * 16 + lr) * 64 + ((lg * 16) ^ axor));
#pragma unroll
    for (int j = 0; j < 2; ++j)
      bf[j] = *(const short8*)(Bc + (wc * 32 + j * 16 + lr) * 64 + ((lg * 16) ^ axor));
#pragma unroll
    for (int i = 0; i < 2; ++i)
#pragma unroll
      for (int j = 0; j < 2; ++j)
        acc[i][j] = __builtin_amdgcn_mfma_f32_16x16x32_bf16(bf[j], af[i], acc[i][j], 0, 0, 0);
    cur ^= 1;
  }
}

// GEMM1: qkv = x_bf16 @ WqkvT^T + bqkv -> Q[b,s,h,d] (pre-scaled 1/8), K[b,s,h,d],
// V^T[b,h,d,s]. grid 768 1-D with XCD swizzle.
__global__ __launch_bounds__(256) void gemm_qkv_kernel(
    const u16* __restrict__ A, const u16* __restrict__ Bt, const float* __restrict__ bias,
    u16* __restrict__ Qb, u16* __restrict__ Kb, u16* __restrict__ Vt) {
  __shared__ __align__(16) u16 As[2 * 128 * 32];
  __shared__ __align__(16) u16 Bs[2 * 128 * 32];
  f32x4 acc[4][4];
  const f32x4 z = {0.f, 0.f, 0.f, 0.f};
#pragma unroll
  for (int i = 0; i < 4; ++i)
#pragma unroll
    for (int j = 0; j < 4; ++j) acc[i][j] = z;
  int lin = blockIdx.x;
  int swz = (lin & 7) * 96 + (lin >> 3);  // 768 = 8*96, bijective
  int n0 = (swz % 24) * 128, m0 = (swz / 24) * 128;
  gemm_tile_mainloop(A, Bt, m0, n0, 1024, As, Bs, acc);

  const int lane = threadIdx.x & 63, wid = threadIdx.x >> 6;
  const int wr = wid >> 1, wc = wid & 1, lr = lane & 15, lg = lane >> 4;
#pragma unroll
  for (int i = 0; i < 4; ++i) {
    int m = m0 + wr * 64 + i * 16 + lr;  // token row
#pragma unroll
    for (int j = 0; j < 4; ++j) {
      int nb = n0 + wc * 64 + j * 16 + lg * 4;  // col base, +r consecutive
      float4 bv = *(const float4*)&bias[nb];
      int c3 = nb >> 10;
      if (c3 == 2) {  // V^T: 4 consecutive d at fixed s -> scalar stores
        int bb = m >> 11, ss = m & 2047;
        int hh = (nb >> 6) & 15, dd = nb & 63;
        size_t vb_ = (((size_t)bb * 16 + hh) * 64 + dd) * 2048 + ss;
        Vt[vb_] = f2bf(acc[i][j][0] + bv.x);
        Vt[vb_ + 2048] = f2bf(acc[i][j][1] + bv.y);
        Vt[vb_ + 4096] = f2bf(acc[i][j][2] + bv.z);
        Vt[vb_ + 6144] = f2bf(acc[i][j][3] + bv.w);
      } else {
        u16* dst = (c3 == 0) ? Qb : Kb;
        float qs = (c3 == 0) ? 0.125f : 1.0f;  // fold 1/sqrt(dh) into Q
        u16x4 o = {f2bf((acc[i][j][0] + bv.x) * qs), f2bf((acc[i][j][1] + bv.y) * qs),
                   f2bf((acc[i][j][2] + bv.z) * qs), f2bf((acc[i][j][3] + bv.w) * qs)};
        *(u16x4*)&dst[(size_t)m * 1024 + (nb & 1023)] = o;
      }
    }
  }
}

// GEMM2: out = (attn_bf16 @ WoT^T + bo) * scale[b], fp32 out. 64x64 tiles, grid 1024 1-D.
__global__ __launch_bounds__(256) void gemm_out_kernel(
    const u16* __restrict__ A, const u16* __restrict__ Bt, const float* __restrict__ bo,
    const float* __restrict__ scale, float* __restrict__ out) {
  __shared__ __align__(16) u16 As[2 * 64 * 32];
  __shared__ __align__(16) u16 Bs[2 * 64 * 32];
  f32x4 acc[2][2];
  const f32x4 z = {0.f, 0.f, 0.f, 0.f};
#pragma unroll
  for (int i = 0; i < 2; ++i)
#pragma unroll
    for (int j = 0; j < 2; ++j) acc[i][j] = z;
  int lin = blockIdx.x;
  int swz = (lin & 7) * 128 + (lin >> 3);  // 1024 = 8*128, bijective
  int n0 = (swz & 15) * 64, m0 = (swz >> 4) * 64;
  gemm64_mainloop(A, Bt, m0, n0, 1024, As, Bs, acc);

  const int lane = threadIdx.x & 63, wid = threadIdx.x >> 6;
  const int wr = wid >> 1, wc = wid & 1, lr = lane & 15, lg = lane >> 4;
#pragma unroll
  for (int i = 0; i < 2; ++i) {
    int m = m0 + wr * 32 + i * 16 + lr;
    float sc = scale[m >> 11];
#pragma unroll
    for (int j = 0; j < 2; ++j) {
      int nb = n0 + wc * 32 + j * 16 + lg * 4;
      float4 bv = *(const float4*)&bo[nb];
      float4 o = {(acc[i][j][0] + bv.x) * sc, (acc[i][j][1] + bv.y) * sc,
                  (acc[i][j][2] + bv.z) * sc, (acc[i][j][3] + bv.w) * sc};
      *(float4*)&out[(size_t)m * 1024 + nb] = o;
    }
  }
}

// ---------- flash attention with mobius score transform ----------
// grid 1024 = [b 2][h 16][qtile 32], 512 thr = 8 waves. Wave (qg = w>>1, half = w&1)
// computes 16 queries x the `half` 32-key slice of each 64-key tile: 2x the waves of r6
// (8192 total = up to 32/CU), each with half the serial work -> latency hiding.
// QK^T = mfma(kf, qf): sacc col = query = lane&15, row = key. PV = mfma(vf, pf):
// acc_o col = query (corr/linv lane-local), row = d. K/V LDS dbuf + XOR swizzle,
// gll16-staged (1 ld/thread/tile). P roundtrip stays within the wave's own Ps half
// (no extra barrier). Epilogue merges half-pairs' (m,l,acc_o) via LDS.
__global__ __launch_bounds__(512, 6) void attn_kernel(
    const u16* __restrict__ Qb, const u16* __restrict__ Kb, const u16* __restrict__ Vt,
    const float* __restrict__ mobius, u16* __restrict__ O) {
  __shared__ __align__(16) char smem[40960];
  u16* Ks = (u16*)smem;              // [2][64*64]
  u16* Vs = (u16*)(smem + 16384);    // [2][64*64] V^T tile: [d][key]
  u16* Ps = (u16*)(smem + 32768);    // [64 q][64 key]
  const int tid = threadIdx.x;
  const int lane = tid & 63, w = tid >> 6;
  const int qg = w >> 1, half = w & 1;
  const int lr = lane & 15, lg = lane >> 4;
  // XCD-aware bijective swizzle (1024 = 8*128): each XCD owns 4 whole (b,h) groups.
  const int bid = blockIdx.x;
  const int bidx = (bid & 7) * 128 + (bid >> 3);
  const int qb = bidx & 31, h = (bidx >> 5) & 15, b = bidx >> 9;
  const float msc = mobius[h];

  const int srow = tid >> 3;                      // staging row (0..63)
  const int scol = ((tid & 7) ^ (srow & 7)) * 8;  // pre-swizzled source col (u16)
  const int rxor = (lr & 7) << 4;                 // read-side swizzle (bytes)

  // Q fragments in registers (Q pre-scaled by 1/8): q = qb*64 + qg*16 + lr
  const u16* qgl = Qb + (size_t)(b * 2048 + qb * 64 + qg * 16 + lr) * 1024 + h * 64 + lg * 8;
  short8 qf0 = *(const short8*)qgl;
  short8 qf1 = *(const short8*)(qgl + 32);

  const u16* kg = Kb + (size_t)(b * 2048 + srow) * 1024 + h * 64 + scol;
  const u16* vg = Vt + ((size_t)(b * 16 + h) * 64 + srow) * 2048 + scol;

  // prologue: stage K/V tile 0 into buffer 0 (512 thr x 16B = full 8KB tile each)
  gll16(kg, Ks + tid * 8);
  gll16(vg, Vs + tid * 8);

  float m_run = -3.0e38f, l_run = 0.0f;  // m in log2 domain
  f32x4 acc_o[4];
  const f32x4 z = {0.f, 0.f, 0.f, 0.f};
#pragma unroll
  for (int i = 0; i < 4; ++i) acc_o[i] = z;

  const float L2E = 1.44269504f;
  const f32x2 one2 = {1.0f, 1.0f};
  const f32x2 msc2 = {msc, msc};
  const f32x2 l2e2 = {L2E, L2E};
  const int ki0 = half * 2;         // this wave's two 16-key row-blocks
  const int qrow = qg * 16 + lr;
  const char* Pc = (const char*)Ps;
  int cur = 0;
  for (int kt = 0; kt < 32; ++kt) {
    __syncthreads();  // buffer `cur` staged; all waves done with cur^1
    if (kt < 31) {    // stage next K/V tile; overlaps with compute below
      int nb = (cur ^ 1) * 4096;
      gll16(kg + (size_t)(kt + 1) * 64 * 1024, Ks + nb + tid * 8);
      gll16(vg + (kt + 1) * 64, Vs + nb + tid * 8);
    }
    const char* Kc = (const char*)(Ks + cur * 4096);
    const char* Vc = (const char*)(Vs + cur * 4096);

    // St(half) = K_slice @ Q_wave^T : 32 keys x 16 q
    f32x4 sacc[2];
#pragma unroll
    for (int i = 0; i < 2; ++i) sacc[i] = z;
    __builtin_amdgcn_s_setprio(1);
#pragma unroll
    for (int kk = 0; kk < 2; ++kk) {
      int krow = (ki0 + kk) * 16 + lr;
      short8 kfa = *(const short8*)(Kc + krow * 128 + ((lg * 16) ^ rxor));
      sacc[kk] = __builtin_amdgcn_mfma_f32_16x16x32_bf16(kfa, qf0, sacc[kk], 0, 0, 0);
      short8 kfb = *(const short8*)(Kc + krow * 128 + ((64 + lg * 16) ^ rxor));
      sacc[kk] = __builtin_amdgcn_mfma_f32_16x16x32_bf16(kfb, qf1, sacc[kk], 0, 0, 0);
    }
    __builtin_amdgcn_s_setprio(0);

    // mobius transform, log2 domain: tl = (s + msc*s/(1+s^2)) * log2(e). 8 elems/lane.
    f32x2 p2[4];
    f32x2 mx = {-3.0e38f, -3.0e38f};
#pragma unroll
    for (int i = 0; i < 4; ++i) {
      int kk = i >> 1, jj = i & 1;
      f32x2 s = {sacc[kk][jj * 2], sacc[kk][jj * 2 + 1]};
      f32x2 d = s * s + one2;
      f32x2 rr = {__builtin_amdgcn_rcpf(d.x), __builtin_amdgcn_rcpf(d.y)};
      f32x2 tl = (msc2 * (s * rr) + s) * l2e2;
      p2[i] = tl;
      mx = __builtin_elementwise_max(mx, tl);
    }
    float tmax = fmaxf(mx.x, mx.y);
    tmax = fmaxf(tmax, __shfl_xor(tmax, 16));
    tmax = fmaxf(tmax, __shfl_xor(tmax, 32));
    // defer-max: only rescale when the running max grew by > 8 (2^8 headroom in P)
    if (__any(tmax > m_run + 8.0f)) {
      float m_new = fmaxf(m_run, tmax);
      float corr = __builtin_amdgcn_exp2f(m_run - m_new);  // per-lane = per-query
      m_run = m_new;
      l_run *= corr;
#pragma unroll
      for (int di = 0; di < 4; ++di)
#pragma unroll
        for (int r = 0; r < 4; ++r) acc_o[di][r] *= corr;
    }
    f32x2 m2 = {m_run, m_run};
    f32x2 sum2 = {0.f, 0.f};
#pragma unroll
    for (int i = 0; i < 4; ++i) {
      f32x2 e = p2[i] - m2;
      f32x2 pe = {__builtin_amdgcn_exp2f(e.x), __builtin_amdgcn_exp2f(e.y)};
      p2[i] = pe;
      sum2 += pe;
    }
    float tsum = sum2.x + sum2.y;
    tsum += __shfl_xor(tsum, 16);
    tsum += __shfl_xor(tsum, 32);
    l_run += tsum;

    // write P (bf16 via cvt_pk) into this wave's own key-half of its q-rows (swizzled)
#pragma unroll
    for (int kk = 0; kk < 2; ++kk) {
      u32x2 pw = {cvtpk_bf16(p2[2 * kk].x, p2[2 * kk].y),
                  cvtpk_bf16(p2[2 * kk + 1].x, p2[2 * kk + 1].y)};
      *(u32x2*)(Pc + qrow * 128 + (((ki0 + kk) * 32 + lg * 8) ^ rxor)) = pw;
    }

    // O += V^T-slice x P-slice (keys half*32..+32; col=query lane-local, row=d)
    __builtin_amdgcn_s_setprio(1);
    {
      int cbx = (half * 64 + lg * 16) ^ rxor;
      short8 pf = *(const short8*)(Pc + qrow * 128 + cbx);
#pragma unroll
      for (int di = 0; di < 4; ++di) {
        short8 vf = *(const short8*)(Vc + (di * 16 + lr) * 128 + cbx);
        acc_o[di] = __builtin_amdgcn_mfma_f32_16x16x32_bf16(vf, pf, acc_o[di], 0, 0, 0);
      }
    }
    __builtin_amdgcn_s_setprio(0);
    cur ^= 1;
  }

  // ---- merge half-pairs: odd waves export (m,l,acc) via LDS; even waves combine ----
  __syncthreads();  // all tile compute done; smem reusable
  float* xch = (float*)smem;  // [4 qg][64 lane][18]
  if (half) {
    float* dst = xch + ((qg * 64) + lane) * 18;
#pragma unroll
    for (int di = 0; di < 4; ++di)
#pragma unroll
      for (int r = 0; r < 4; ++r) dst[di * 4 + r] = acc_o[di][r];
    dst[16] = m_run;
    dst[17] = l_run;
  }
  __syncthreads();
  if (!half) {
    const float* src = xch + ((qg * 64) + lane) * 18;
    float m1 = src[16], l1 = src[17];
    float m01 = fmaxf(m_run, m1);
    float a0 = __builtin_amdgcn_exp2f(m_run - m01);
    float a1 = __builtin_amdgcn_exp2f(m1 - m01);
    float linv = 1.0f / (l_run * a0 + l1 * a1);
    size_t obase = ((size_t)(b * 2048 + qb * 64 + qg * 16 + lr)) * 1024 + h * 64;
#pragma unroll
    for (int di = 0; di < 4; ++di) {
      float o0 = (acc_o[di][0] * a0 + src[di * 4 + 0] * a1) * linv;
      float o1 = (acc_o[di][1] * a0 + src[di * 4 + 1] * a1) * linv;
      float o2 = (acc_o[di][2] * a0 + src[di * 4 + 2] * a1) * linv;
      float o3 = (acc_o[di][3] * a0 + src[di * 4 + 3] * a1) * linv;
      u32x2 o = {cvtpk_bf16(o0, o1), cvtpk_bf16(o2, o3)};
      *(u32x2*)&O[obase + di * 16 + lg * 4] = o;
    }
  }
}

// ---------- launch ----------

extern "C" void kernel_launch(void* const* d_in, const int* in_sizes, int n_in,
                              void* d_out, int out_size, void* d_ws, size_t ws_size,
                              hipStream_t stream) {
  const float* x = (const float*)d_in[0];
  const float* Wqkv = (const float*)d_in[1];
  const float* bqkv = (const float*)d_in[2];
  const float* Wo = (const float*)d_in[3];
  const float* bo = (const float*)d_in[4];
  const float* mob = (const float*)d_in[5];
  const float* W1 = (const float*)d_in[6];
  const float* b1 = (const float*)d_in[7];
  const float* W2 = (const float*)d_in[8];
  const float* b2 = (const float*)d_in[9];
  const float* aw = (const float*)d_in[10];
  float* out = (float*)d_out;

  const size_t MB = 1024 * 1024;
  char* ws = (char*)d_ws;
  float* scale = (float*)ws;           // 2 floats
  float* ctx = (float*)(ws + 256);     // 2048 floats
  float* hbuf = (float*)(ws + 16384);  // 2x512 floats
  char* base = ws + 32768;
  u16* xbf = (u16*)base;               // 8MB
  u16* wqkvT = (u16*)(base + 8 * MB);  // 6MB
  u16* woT = (u16*)(base + 14 * MB);   // 2MB
  u16* Qb = (u16*)(base + 16 * MB);    // 8MB [B,S,H,64] (pre-scaled by 1/8)
  u16* Kb = (u16*)(base + 24 * MB);    // 8MB [B,S,H,64]
  u16* Vt = (u16*)(base + 32 * MB);    // 8MB [B,H,64,S]
  u16* attn = (u16*)(base + 40 * MB);  // 8MB [B,S,D]
  // total = 32KB + 48MB

  hipMemsetAsync(ctx, 0, 2048 * sizeof(float), stream);
  ctx_cvt_kernel<<<256, 256, 0, stream>>>(x, ctx, xbf);
  adaptive1_kernel<<<32, 256, 0, stream>>>(ctx, W1, b1, hbuf);
  adaptive2_kernel<<<2, 256, 0, stream>>>(hbuf, W2, b2, aw, scale);
  transpose_bf16_kernel<<<dim3(96, 32), 256, 0, stream>>>(Wqkv, wqkvT, 1024, 3072);
  transpose_bf16_kernel<<<dim3(32, 32), 256, 0, stream>>>(Wo, woT, 1024, 1024);
  gemm_qkv_kernel<<<768, 256, 0, stream>>>(xbf, wqkvT, bqkv, Qb, Kb, Vt);
  attn_kernel<<<1024, 512, 0, stream>>>(Qb, Kb, Vt, mob, attn);
  gemm_out_kernel<<<1024, 256, 0, stream>>>(attn, woT, bo, scale, out);
}

// Round 9
// 257.001 us; speedup vs baseline: 1.3285x; 1.0117x over previous
//
#include <hip/hip_runtime.h>
#include <hip/hip_bf16.h>
#include <stdint.h>

typedef unsigned short u16;
typedef unsigned int u32;
typedef __attribute__((ext_vector_type(8))) short short8;   // 8 bf16 (4 VGPRs) MFMA operand
typedef __attribute__((ext_vector_type(4))) float f32x4;    // MFMA accumulator
typedef __attribute__((ext_vector_type(2))) float f32x2;    // packed-fp32 (v_pk_*) carrier
typedef __attribute__((ext_vector_type(4))) unsigned short u16x4;
typedef __attribute__((ext_vector_type(2))) unsigned int u32x2;

#define DEVFN static __device__ __forceinline__

// ---------- helpers ----------

DEVFN u16 f2bf(float f) {  // RNE float->bf16 (finite inputs)
  u32 u = __float_as_uint(f);
  u = (u + 0x7FFFu + ((u >> 16) & 1u)) >> 16;
  return (u16)u;
}

DEVFN u32 cvtpk_bf16(float lo, float hi) {  // T12: packed f32x2 -> 2xbf16 in one u32
  u32 r;
  asm("v_cvt_pk_bf16_f32 %0, %1, %2" : "=v"(r) : "v"(lo), "v"(hi));
  return r;
}

DEVFN void gll16(const void* g, void* l) {  // async global->LDS, 16B/lane
  __builtin_amdgcn_global_load_lds((const __attribute__((address_space(1))) u32*)g,
                                   (__attribute__((address_space(3))) u32*)l, 16, 0, 0);
}

// ---------- fused context-sum + bf16 convert (single pass over x) ----------
// grid 256 = [b 2][128 chunks of 16 rows]; 256 threads; thread owns 4 consecutive cols.
__global__ void ctx_cvt_kernel(const float* __restrict__ x, float* __restrict__ ctx,
                               u16* __restrict__ xbf) {
  int blk = blockIdx.x;
  int b = blk >> 7;
  int s0 = (blk & 127) * 16;
  int t = threadIdx.x;
  const float* xb = x + ((size_t)b * 2048 + s0) * 1024 + t * 4;
  u16* ob = xbf + ((size_t)b * 2048 + s0) * 1024 + t * 4;
  float4 sum = {0.f, 0.f, 0.f, 0.f};
#pragma unroll
  for (int s = 0; s < 16; ++s) {
    float4 v = *(const float4*)(xb + (size_t)s * 1024);
    sum.x += v.x;
    sum.y += v.y;
    sum.z += v.z;
    sum.w += v.w;
    u16x4 o = {f2bf(v.x), f2bf(v.y), f2bf(v.z), f2bf(v.w)};
    *(u16x4*)(ob + (size_t)s * 1024) = o;
  }
  float* c = ctx + b * 1024 + t * 4;
  atomicAdd(c + 0, sum.x);
  atomicAdd(c + 1, sum.y);
  atomicAdd(c + 2, sum.z);
  atomicAdd(c + 3, sum.w);
}

// stage 1: h = gelu(ctx/2048 @ W1 + b1). grid 256 = [b 2][jg 128 chunks of 4 j];
// 256 thr = 64 d-parts x 4 j. LDS tree reduce over d-parts.
__global__ void adaptive1_kernel(const float* __restrict__ ctx, const float* __restrict__ W1,
                                 const float* __restrict__ b1, float* __restrict__ hbuf) {
  int b = blockIdx.x >> 7, jg = blockIdx.x & 127;
  int t = threadIdx.x;
  int jl = t & 3, dp = t >> 2;
  int j = jg * 4 + jl;
  __shared__ float ctxs[1024];
  __shared__ float partial[256];
  for (int i = t; i < 1024; i += 256) ctxs[i] = ctx[b * 1024 + i] * (1.0f / 2048.0f);
  __syncthreads();
  float a0 = 0.f, a1 = 0.f;
  int d0 = dp * 16;
#pragma unroll
  for (int d = d0; d < d0 + 16; d += 2) {
    a0 += ctxs[d] * W1[(size_t)d * 512 + j];
    a1 += ctxs[d + 1] * W1[(size_t)(d + 1) * 512 + j];
  }
  partial[t] = a0 + a1;
  __syncthreads();
  for (int off = 128; off >= 4; off >>= 1) {
    if (t < off) partial[t] += partial[t + off];
    __syncthreads();
  }
  if (t < 4) {
    float acc = b1[jg * 4 + t] + partial[t];
    hbuf[b * 512 + jg * 4 + t] =
        0.5f * acc * (1.0f + erff(acc * 0.70710678118654752f));  // exact gelu
  }
}

// stage 2: af = sigmoid(h @ W2 + b2); scale[b] = 1 + aw*mean(af). grid 2.
__global__ void adaptive2_kernel(const float* __restrict__ hbuf, const float* __restrict__ W2,
                                 const float* __restrict__ b2, const float* __restrict__ aw,
                                 float* __restrict__ scale) {
  int b = blockIdx.x;
  int t = threadIdx.x;
  __shared__ float part[256];
  int o = t & 15, seg = t >> 4;  // 16 segs x 32 j's
  float a = 0.f;
  for (int j = seg * 32; j < seg * 32 + 32; ++j) a += hbuf[b * 512 + j] * W2[(size_t)j * 16 + o];
  part[t] = a;
  __syncthreads();
  if (t < 16) {
    float acc = b2[t];
    for (int s2 = 0; s2 < 16; ++s2) acc += part[s2 * 16 + t];
    part[t] = 1.0f / (1.0f + __expf(-acc));
  }
  __syncthreads();
  if (t == 0) {
    float s = 0.f;
    for (int i = 0; i < 16; ++i) s += part[i];
    scale[b] = 1.0f + aw[0] * (s * (1.0f / 16.0f));
  }
}

// fused transposes: fp32 [K][N] -> bf16 [N][K]. blocks 0..3071: Wqkv (N=3072);
// 3072..4095: Wo (N=1024). 32x32 tiles, 256 thr.
__global__ void transpose_both_kernel(const float* __restrict__ Wqkv, u16* __restrict__ wqkvT,
                                      const float* __restrict__ Wo, u16* __restrict__ woT) {
  __shared__ u16 tile[32][33];
  int bid = blockIdx.x;
  const float* in;
  u16* out;
  int N, n0, k0;
  if (bid < 3072) {
    in = Wqkv; out = wqkvT; N = 3072;
    n0 = (bid % 96) * 32; k0 = (bid / 96) * 32;
  } else {
    bid -= 3072;
    in = Wo; out = woT; N = 1024;
    n0 = (bid & 31) * 32; k0 = (bid >> 5) * 32;
  }
  int tc = threadIdx.x & 31, tr = threadIdx.x >> 5;  // tr in 0..7
  for (int i = tr; i < 32; i += 8)
    tile[i][tc] = f2bf(in[(size_t)(k0 + i) * N + n0 + tc]);
  __syncthreads();
  for (int i = tr; i < 32; i += 8)
    out[(size_t)(n0 + i) * 1024 + k0 + tc] = tile[tc][i];
}

// ---------- GEMM mainloop: swizzled LDS + 2-phase double-buffer ----------
// C = A(MxK bf16 rowmajor) @ Bt(NxK bf16 rowmajor)^T, fp32 acc. K multiple of 32.
// acc[i][j] = mfma(bf[j], af[i]) -> lane&15 = m-row (i*16+lr), lg*4+r = n-col (j*16+lg*4+r):
// each lane owns 4 CONSECUTIVE output columns -> packed epilogue stores.

// 128x128 tile, 4 waves. As/Bs are [2][128*32] u16.
DEVFN void gemm_tile_mainloop(const u16* __restrict__ A, const u16* __restrict__ Bt,
                              int m0, int n0, int K, u16* As, u16* Bs, f32x4 acc[4][4]) {
  const int tid = threadIdx.x;
  const int lane = tid & 63, wid = tid >> 6;
  const int wr = wid >> 1, wc = wid & 1;
  const int lr = lane & 15, lg = lane >> 4;
  const int srow = tid >> 2;
  const int scol = ((tid & 3) ^ ((tid >> 3) & 3)) * 8;  // pre-swizzled source col (u16)
  const int axor = ((lr >> 1) & 3) << 4;                // read-side swizzle (bytes)

  const u16* ag0 = A + (size_t)(m0 + srow) * K + scol;
  const u16* ag1 = ag0 + (size_t)64 * K;
  const u16* bg0 = Bt + (size_t)(n0 + srow) * K + scol;
  const u16* bg1 = bg0 + (size_t)64 * K;

  // prologue: stage K-step 0 into buffer 0
  gll16(ag0, As + tid * 8);
  gll16(ag1, As + (tid + 256) * 8);
  gll16(bg0, Bs + tid * 8);
  gll16(bg1, Bs + (tid + 256) * 8);

  int cur = 0;
  for (int k0 = 0; k0 < K; k0 += 32) {
    __syncthreads();    // drains vmcnt: buffer `cur` staged & prev compute on cur^1 done
    if (k0 + 32 < K) {  // issue next-step stage; overlaps with compute below
      int nb = (cur ^ 1) * 4096;
      gll16(ag0 + k0 + 32, As + nb + tid * 8);
      gll16(ag1 + k0 + 32, As + nb + (tid + 256) * 8);
      gll16(bg0 + k0 + 32, Bs + nb + tid * 8);
      gll16(bg1 + k0 + 32, Bs + nb + (tid + 256) * 8);
    }
    const char* Ac = (const char*)(As + cur * 4096);
    const char* Bc = (const char*)(Bs + cur * 4096);
    short8 af[4], bf[4];
#pragma unroll
    for (int i = 0; i < 4; ++i)
      af[i] = *(const short8*)(Ac + (wr * 64 + i * 16 + lr) * 64 + ((lg * 16) ^ axor));
#pragma unroll
    for (int j = 0; j < 4; ++j)
      bf[j] = *(const short8*)(Bc + (wc * 64 + j * 16 + lr) * 64 + ((lg * 16) ^ axor));
#pragma unroll
    for (int i = 0; i < 4; ++i)
#pragma unroll
      for (int j = 0; j < 4; ++j)
        acc[i][j] = __builtin_amdgcn_mfma_f32_16x16x32_bf16(bf[j], af[i], acc[i][j], 0, 0, 0);
    cur ^= 1;
  }
}

// GEMM1: qkv = x_bf16 @ WqkvT^T + bqkv -> Q[b,s,h,d] (pre-scaled 1/8), K[b,s,h,d],
// V^T[b,h,d,s]. grid 768 1-D with XCD swizzle.
__global__ __launch_bounds__(256) void gemm_qkv_kernel(
    const u16* __restrict__ A, const u16* __restrict__ Bt, const float* __restrict__ bias,
    u16* __restrict__ Qb, u16* __restrict__ Kb, u16* __restrict__ Vt) {
  __shared__ __align__(16) u16 As[2 * 128 * 32];
  __shared__ __align__(16) u16 Bs[2 * 128 * 32];
  f32x4 acc[4][4];
  const f32x4 z = {0.f, 0.f, 0.f, 0.f};
#pragma unroll
  for (int i = 0; i < 4; ++i)
#pragma unroll
    for (int j = 0; j < 4; ++j) acc[i][j] = z;
  int lin = blockIdx.x;
  int swz = (lin & 7) * 96 + (lin >> 3);  // 768 = 8*96, bijective
  int n0 = (swz % 24) * 128, m0 = (swz / 24) * 128;
  gemm_tile_mainloop(A, Bt, m0, n0, 1024, As, Bs, acc);

  const int lane = threadIdx.x & 63, wid = threadIdx.x >> 6;
  const int wr = wid >> 1, wc = wid & 1, lr = lane & 15, lg = lane >> 4;
#pragma unroll
  for (int i = 0; i < 4; ++i) {
    int m = m0 + wr * 64 + i * 16 + lr;  // token row
#pragma unroll
    for (int j = 0; j < 4; ++j) {
      int nb = n0 + wc * 64 + j * 16 + lg * 4;  // col base, +r consecutive
      float4 bv = *(const float4*)&bias[nb];
      int c3 = nb >> 10;
      if (c3 == 2) {  // V^T: 4 consecutive d at fixed s
        int bb = m >> 11, ss = m & 2047;
        int hh = (nb >> 6) & 15, dd = nb & 63;
        size_t vb_ = (((size_t)bb * 16 + hh) * 64 + dd) * 2048 + ss;
        Vt[vb_] = f2bf(acc[i][j][0] + bv.x);
        Vt[vb_ + 2048] = f2bf(acc[i][j][1] + bv.y);
        Vt[vb_ + 4096] = f2bf(acc[i][j][2] + bv.z);
        Vt[vb_ + 6144] = f2bf(acc[i][j][3] + bv.w);
      } else {
        u16* dst = (c3 == 0) ? Qb : Kb;
        float qs = (c3 == 0) ? 0.125f : 1.0f;  // fold 1/sqrt(dh) into Q (exact pow2 scale)
        u16x4 o = {f2bf((acc[i][j][0] + bv.x) * qs), f2bf((acc[i][j][1] + bv.y) * qs),
                   f2bf((acc[i][j][2] + bv.z) * qs), f2bf((acc[i][j][3] + bv.w) * qs)};
        *(u16x4*)&dst[(size_t)m * 1024 + (nb & 1023)] = o;
      }
    }
  }
}

// GEMM2: out = (attn_bf16 @ WoT^T + bo) * scale[b], fp32 out. 128x128 tiles, grid 256 1-D.
__global__ __launch_bounds__(256) void gemm_out_kernel(
    const u16* __restrict__ A, const u16* __restrict__ Bt, const float* __restrict__ bo,
    const float* __restrict__ scale, float* __restrict__ out) {
  __shared__ __align__(16) u16 As[2 * 128 * 32];
  __shared__ __align__(16) u16 Bs[2 * 128 * 32];
  f32x4 acc[4][4];
  const f32x4 z = {0.f, 0.f, 0.f, 0.f};
#pragma unroll
  for (int i = 0; i < 4; ++i)
#pragma unroll
    for (int j = 0; j < 4; ++j) acc[i][j] = z;
  int lin = blockIdx.x;
  int swz = (lin & 7) * 32 + (lin >> 3);  // 256 = 8*32, bijective
  int n0 = (swz & 7) * 128, m0 = (swz >> 3) * 128;
  gemm_tile_mainloop(A, Bt, m0, n0, 1024, As, Bs, acc);

  const int lane = threadIdx.x & 63, wid = threadIdx.x >> 6;
  const int wr = wid >> 1, wc = wid & 1, lr = lane & 15, lg = lane >> 4;
#pragma unroll
  for (int i = 0; i < 4; ++i) {
    int m = m0 + wr * 64 + i * 16 + lr;
    float sc = scale[m >> 11];
#pragma unroll
    for (int j = 0; j < 4; ++j) {
      int nb = n0 + wc * 64 + j * 16 + lg * 4;
      float4 bv = *(const float4*)&bo[nb];
      float4 o = {(acc[i][j][0] + bv.x) * sc, (acc[i][j][1] + bv.y) * sc,
                  (acc[i][j][2] + bv.z) * sc, (acc[i][j][3] + bv.w) * sc};
      *(float4*)&out[(size_t)m * 1024 + nb] = o;
    }
  }
}

// ---------- flash attention with mobius score transform (r7 passing version) ----------
// grid 1024 = [b 2][h 16][qtile 32], 512 thr = 8 waves. Wave (qg = w>>1, half = w&1)
// computes 16 queries x the `half` 32-key slice of each 64-key tile.
// QK^T = mfma(kf, qf): sacc col = query = lane&15, row = key. PV = mfma(vf, pf):
// acc_o col = query (corr/linv lane-local), row = d. K/V LDS dbuf + XOR swizzle,
// gll16-staged. Epilogue merges half-pairs' (m,l,acc_o) via LDS.
__global__ __launch_bounds__(512, 6) void attn_kernel(
    const u16* __restrict__ Qb, const u16* __restrict__ Kb, const u16* __restrict__ Vt,
    const float* __restrict__ mobius, u16* __restrict__ O) {
  __shared__ __align__(16) char smem[40960];
  u16* Ks = (u16*)smem;            // [2][64*64]
  u16* Vs = (u16*)(smem + 16384);  // [2][64*64] V^T tile: [d][key]
  u16* Ps = (u16*)(smem + 32768);  // [64 q][64 key]
  const int tid = threadIdx.x;
  const int lane = tid & 63, w = tid >> 6;
  const int qg = w >> 1, half = w & 1;
  const int lr = lane & 15, lg = lane >> 4;
  // XCD-aware bijective swizzle (1024 = 8*128): each XCD owns 4 whole (b,h) groups.
  const int bid = blockIdx.x;
  const int bidx = (bid & 7) * 128 + (bid >> 3);
  const int qb = bidx & 31, h = (bidx >> 5) & 15, b = bidx >> 9;
  const float msc = mobius[h];

  const int srow = tid >> 3;                      // staging row (0..63)
  const int scol = ((tid & 7) ^ (srow & 7)) * 8;  // pre-swizzled source col (u16)
  const int rxor = (lr & 7) << 4;                 // read-side swizzle (bytes)

  // Q fragments in registers (Q pre-scaled by 1/8): q = qb*64 + qg*16 + lr
  const u16* qgl = Qb + (size_t)(b * 2048 + qb * 64 + qg * 16 + lr) * 1024 + h * 64 + lg * 8;
  short8 qf0 = *(const short8*)qgl;
  short8 qf1 = *(const short8*)(qgl + 32);

  const u16* kg = Kb + (size_t)(b * 2048 + srow) * 1024 + h * 64 + scol;
  const u16* vg = Vt + ((size_t)(b * 16 + h) * 64 + srow) * 2048 + scol;

  // prologue: stage K/V tile 0 into buffer 0 (512 thr x 16B = full 8KB tile each)
  gll16(kg, Ks + tid * 8);
  gll16(vg, Vs + tid * 8);

  float m_run = -3.0e38f, l_run = 0.0f;  // m in log2 domain
  f32x4 acc_o[4];
  const f32x4 z = {0.f, 0.f, 0.f, 0.f};
#pragma unroll
  for (int i = 0; i < 4; ++i) acc_o[i] = z;

  const float L2E = 1.44269504f;
  const f32x2 one2 = {1.0f, 1.0f};
  const f32x2 msc2 = {msc, msc};
  const f32x2 l2e2 = {L2E, L2E};
  const int ki0 = half * 2;  // this wave's two 16-key row-blocks
  const int qrow = qg * 16 + lr;
  const char* Pc = (const char*)Ps;
  int cur = 0;
  for (int kt = 0; kt < 32; ++kt) {
    __syncthreads();  // buffer `cur` staged; all waves done with cur^1
    if (kt < 31) {    // stage next K/V tile; overlaps with compute below
      int nb = (cur ^ 1) * 4096;
      gll16(kg + (size_t)(kt + 1) * 64 * 1024, Ks + nb + tid * 8);
      gll16(vg + (kt + 1) * 64, Vs + nb + tid * 8);
    }
    const char* Kc = (const char*)(Ks + cur * 4096);
    const char* Vc = (const char*)(Vs + cur * 4096);

    // St(half) = K_slice @ Q_wave^T : 32 keys x 16 q
    f32x4 sacc[2];
#pragma unroll
    for (int i = 0; i < 2; ++i) sacc[i] = z;
    __builtin_amdgcn_s_setprio(1);
#pragma unroll
    for (int kk = 0; kk < 2; ++kk) {
      int krow = (ki0 + kk) * 16 + lr;
      short8 kfa = *(const short8*)(Kc + krow * 128 + ((lg * 16) ^ rxor));
      sacc[kk] = __builtin_amdgcn_mfma_f32_16x16x32_bf16(kfa, qf0, sacc[kk], 0, 0, 0);
      short8 kfb = *(const short8*)(Kc + krow * 128 + ((64 + lg * 16) ^ rxor));
      sacc[kk] = __builtin_amdgcn_mfma_f32_16x16x32_bf16(kfb, qf1, sacc[kk], 0, 0, 0);
    }
    __builtin_amdgcn_s_setprio(0);

    // mobius transform, log2 domain: tl = (s + msc*s/(1+s^2)) * log2(e). 8 elems/lane.
    f32x2 p2[4];
    f32x2 mx = {-3.0e38f, -3.0e38f};
#pragma unroll
    for (int i = 0; i < 4; ++i) {
      int kk = i >> 1, jj = i & 1;
      f32x2 s = {sacc[kk][jj * 2], sacc[kk][jj * 2 + 1]};
      f32x2 d = s * s + one2;
      f32x2 rr = {__builtin_amdgcn_rcpf(d.x), __builtin_amdgcn_rcpf(d.y)};
      f32x2 tl = (msc2 * (s * rr) + s) * l2e2;
      p2[i] = tl;
      mx = __builtin_elementwise_max(mx, tl);
    }
    float tmax = fmaxf(mx.x, mx.y);
    tmax = fmaxf(tmax, __shfl_xor(tmax, 16));
    tmax = fmaxf(tmax, __shfl_xor(tmax, 32));
    // defer-max: only rescale when the running max grew by > 8 (2^8 headroom in P)
    if (__any(tmax > m_run + 8.0f)) {
      float m_new = fmaxf(m_run, tmax);
      float corr = __builtin_amdgcn_exp2f(m_run - m_new);  // per-lane = per-query
      m_run = m_new;
      l_run *= corr;
#pragma unroll
      for (int di = 0; di < 4; ++di)
#pragma unroll
        for (int r = 0; r < 4; ++r) acc_o[di][r] *= corr;
    }
    f32x2 m2 = {m_run, m_run};
    f32x2 sum2 = {0.f, 0.f};
#pragma unroll
    for (int i = 0; i < 4; ++i) {
      f32x2 e = p2[i] - m2;
      f32x2 pe = {__builtin_amdgcn_exp2f(e.x), __builtin_amdgcn_exp2f(e.y)};
      p2[i] = pe;
      sum2 += pe;
    }
    float tsum = sum2.x + sum2.y;
    tsum += __shfl_xor(tsum, 16);
    tsum += __shfl_xor(tsum, 32);
    l_run += tsum;

    // write P (bf16 via cvt_pk) into this wave's own key-half of its q-rows (swizzled)
#pragma unroll
    for (int kk = 0; kk < 2; ++kk) {
      u32x2 pw = {cvtpk_bf16(p2[2 * kk].x, p2[2 * kk].y),
                  cvtpk_bf16(p2[2 * kk + 1].x, p2[2 * kk + 1].y)};
      *(u32x2*)(Pc + qrow * 128 + (((ki0 + kk) * 32 + lg * 8) ^ rxor)) = pw;
    }

    // O += V^T-slice x P-slice (keys half*32..+32; col=query lane-local, row=d)
    __builtin_amdgcn_s_setprio(1);
    {
      int cbx = (half * 64 + lg * 16) ^ rxor;
      short8 pf = *(const short8*)(Pc + qrow * 128 + cbx);
#pragma unroll
      for (int di = 0; di < 4; ++di) {
        short8 vf = *(const short8*)(Vc + (di * 16 + lr) * 128 + cbx);
        acc_o[di] = __builtin_amdgcn_mfma_f32_16x16x32_bf16(vf, pf, acc_o[di], 0, 0, 0);
      }
    }
    __builtin_amdgcn_s_setprio(0);
    cur ^= 1;
  }

  // ---- merge half-pairs: odd waves export (m,l,acc) via LDS; even waves combine ----
  __syncthreads();  // all tile compute done; smem reusable
  float* xch = (float*)smem;  // [4 qg][64 lane][18]
  if (half) {
    float* dst = xch + ((qg * 64) + lane) * 18;
#pragma unroll
    for (int di = 0; di < 4; ++di)
#pragma unroll
      for (int r = 0; r < 4; ++r) dst[di * 4 + r] = acc_o[di][r];
    dst[16] = m_run;
    dst[17] = l_run;
  }
  __syncthreads();
  if (!half) {
    const float* src = xch + ((qg * 64) + lane) * 18;
    float m1 = src[16], l1 = src[17];
    float m01 = fmaxf(m_run, m1);
    float a0 = __builtin_amdgcn_exp2f(m_run - m01);
    float a1 = __builtin_amdgcn_exp2f(m1 - m01);
    float linv = 1.0f / (l_run * a0 + l1 * a1);
    size_t obase = ((size_t)(b * 2048 + qb * 64 + qg * 16 + lr)) * 1024 + h * 64;
#pragma unroll
    for (int di = 0; di < 4; ++di) {
      float o0 = (acc_o[di][0] * a0 + src[di * 4 + 0] * a1) * linv;
      float o1 = (acc_o[di][1] * a0 + src[di * 4 + 1] * a1) * linv;
      float o2 = (acc_o[di][2] * a0 + src[di * 4 + 2] * a1) * linv;
      float o3 = (acc_o[di][3] * a0 + src[di * 4 + 3] * a1) * linv;
      u32x2 o = {cvtpk_bf16(o0, o1), cvtpk_bf16(o2, o3)};
      *(u32x2*)&O[obase + di * 16 + lg * 4] = o;
    }
  }
}

// ---------- launch ----------

extern "C" void kernel_launch(void* const* d_in, const int* in_sizes, int n_in,
                              void* d_out, int out_size, void* d_ws, size_t ws_size,
                              hipStream_t stream) {
  const float* x = (const float*)d_in[0];
  const float* Wqkv = (const float*)d_in[1];
  const float* bqkv = (const float*)d_in[2];
  const float* Wo = (const float*)d_in[3];
  const float* bo = (const float*)d_in[4];
  const float* mob = (const float*)d_in[5];
  const float* W1 = (const float*)d_in[6];
  const float* b1 = (const float*)d_in[7];
  const float* W2 = (const float*)d_in[8];
  const float* b2 = (const float*)d_in[9];
  const float* aw = (const float*)d_in[10];
  float* out = (float*)d_out;

  const size_t MB = 1024 * 1024;
  char* ws = (char*)d_ws;
  float* scale = (float*)ws;           // 2 floats
  float* ctx = (float*)(ws + 256);     // 2048 floats
  float* hbuf = (float*)(ws + 16384);  // 2x512 floats
  char* base = ws + 32768;
  u16* xbf = (u16*)base;               // 8MB
  u16* wqkvT = (u16*)(base + 8 * MB);  // 6MB
  u16* woT = (u16*)(base + 14 * MB);   // 2MB
  u16* Qb = (u16*)(base + 16 * MB);    // 8MB [B,S,H,64] (pre-scaled by 1/8)
  u16* Kb = (u16*)(base + 24 * MB);    // 8MB [B,S,H,64]
  u16* Vt = (u16*)(base + 32 * MB);    // 8MB [B,H,64,S]
  u16* attn = (u16*)(base + 40 * MB);  // 8MB [B,S,D]
  // total = 32KB + 48MB

  hipMemsetAsync(ctx, 0, 2048 * sizeof(float), stream);
  ctx_cvt_kernel<<<256, 256, 0, stream>>>(x, ctx, xbf);
  adaptive1_kernel<<<256, 256, 0, stream>>>(ctx, W1, b1, hbuf);
  adaptive2_kernel<<<2, 256, 0, stream>>>(hbuf, W2, b2, aw, scale);
  transpose_both_kernel<<<4096, 256, 0, stream>>>(Wqkv, wqkvT, Wo, woT);
  gemm_qkv_kernel<<<768, 256, 0, stream>>>(xbf, wqkvT, bqkv, Qb, Kb, Vt);
  attn_kernel<<<1024, 512, 0, stream>>>(Qb, Kb, Vt, mob, attn);
  gemm_out_kernel<<<256, 256, 0, stream>>>(attn, woT, bo, scale, out);
}